// Round 1
// baseline (3126.853 us; speedup 1.0000x reference)
//
#include <hip/hip_runtime.h>
#include <math.h>
#include <stdint.h>
#include <stddef.h>

// ---------------------------------------------------------------------------
// Heterogeneous Graph Transformer + cross-attention, fp32 baseline.
// Sizes (fixed by the problem):
static constexpr int NHEAD = 4;
static constexpr int HDIM  = 64;
static constexpr int HIDF  = 256;   // NHEAD*HDIM
static constexpr int OUTF  = 128;
static constexpr int N0 = 2048, N1 = 4096, N2 = 3072;   // participant, gene, metabolite
static constexpr int E_PG = 250000, E_GP = 250000, E_PM = 200000, E_MP = 200000;
static constexpr float ATT_SCALE = 0.125f;              // 1/sqrt(64)
static constexpr int CH = 1024;                         // cross-attn q-row chunk

enum { M_STORE = 0, M_ADD = 1, M_SKIP = 2, M_ATOMIC = 3 };

__device__ __forceinline__ float gelu_exact(float x) {
    return 0.5f * x * (1.0f + erff(x * 0.7071067811865476f));
}

// ---------------------------------------------------------------------------
// Generic tiled fp32 GEMM. C[M,N] = epilogue(A[M,K] @ B + bias).
//   NT=false: B is [K,N] (ldb).  NT=true: B is [N,K] (ldb) -> C = A @ B^T.
// Head-batched via blockIdx.z: per-z element offsets aoffz/boffz/coffz.
// splitk>1 (mode must be M_ATOMIC): z = head*splitk + kslice.
// Requires: M%64==0, N%64==0, (K/splitk)%16==0, all pointers 16B aligned,
// lda/ldb multiples of 4.
template <bool NT>
__global__ __launch_bounds__(256) void gemm_kernel(
    const float* __restrict__ A, int lda, int aoffz,
    const float* __restrict__ B, int ldb, int boffz,
    float* __restrict__ C, int ldc, int coffz,
    const float* __restrict__ bias,
    int M, int N, int K, int splitk, int mode,
    const float* __restrict__ skipv, const float* __restrict__ Hbuf)
{
    const int z = blockIdx.z;
    const int head = z / splitk, ks = z - head * splitk;
    A += (size_t)head * aoffz;
    B += (size_t)head * boffz;
    C += (size_t)head * coffz;
    const int klen = K / splitk;
    const int kbeg = ks * klen, kend = kbeg + klen;

    __shared__ float As[16][64];
    __shared__ float Bs[16][64];
    const int tid = threadIdx.x;
    const int tx = tid & 15, ty = tid >> 4;
    const int bm = blockIdx.y << 6, bn = blockIdx.x << 6;
    const int alr = tid >> 2, alc = (tid & 3) << 2;      // 64 rows x 4-col chunks
    const int blr = tid >> 4, blc = (tid & 15) << 2;     // 16 rows x 4-col chunks

    float acc[4][4] = {};

    for (int k0 = kbeg; k0 < kend; k0 += 16) {
        float4 av = *(const float4*)(A + (size_t)(bm + alr) * lda + k0 + alc);
        As[alc + 0][alr] = av.x; As[alc + 1][alr] = av.y;
        As[alc + 2][alr] = av.z; As[alc + 3][alr] = av.w;
        if (!NT) {
            float4 bv = *(const float4*)(B + (size_t)(k0 + blr) * ldb + bn + blc);
            *(float4*)&Bs[blr][blc] = bv;
        } else {
            float4 bv = *(const float4*)(B + (size_t)(bn + alr) * ldb + k0 + alc);
            Bs[alc + 0][alr] = bv.x; Bs[alc + 1][alr] = bv.y;
            Bs[alc + 2][alr] = bv.z; Bs[alc + 3][alr] = bv.w;
        }
        __syncthreads();
#pragma unroll
        for (int kk = 0; kk < 16; kk++) {
            const float4 a4 = *(const float4*)&As[kk][ty << 2];
            const float4 b4 = *(const float4*)&Bs[kk][tx << 2];
            acc[0][0] = fmaf(a4.x, b4.x, acc[0][0]);
            acc[0][1] = fmaf(a4.x, b4.y, acc[0][1]);
            acc[0][2] = fmaf(a4.x, b4.z, acc[0][2]);
            acc[0][3] = fmaf(a4.x, b4.w, acc[0][3]);
            acc[1][0] = fmaf(a4.y, b4.x, acc[1][0]);
            acc[1][1] = fmaf(a4.y, b4.y, acc[1][1]);
            acc[1][2] = fmaf(a4.y, b4.z, acc[1][2]);
            acc[1][3] = fmaf(a4.y, b4.w, acc[1][3]);
            acc[2][0] = fmaf(a4.z, b4.x, acc[2][0]);
            acc[2][1] = fmaf(a4.z, b4.y, acc[2][1]);
            acc[2][2] = fmaf(a4.z, b4.z, acc[2][2]);
            acc[2][3] = fmaf(a4.z, b4.w, acc[2][3]);
            acc[3][0] = fmaf(a4.w, b4.x, acc[3][0]);
            acc[3][1] = fmaf(a4.w, b4.y, acc[3][1]);
            acc[3][2] = fmaf(a4.w, b4.z, acc[3][2]);
            acc[3][3] = fmaf(a4.w, b4.w, acc[3][3]);
        }
        __syncthreads();
    }

    float gblend = 0.f, hblend = 0.f;
    if (mode == M_SKIP) {
        float sv = skipv[0];
        gblend = 1.f / (1.f + expf(-sv));
        hblend = 1.f - gblend;
    }
#pragma unroll
    for (int i = 0; i < 4; i++) {
        const int mrow = bm + (ty << 2) + i;
        float* crow = C + (size_t)mrow * ldc + bn + (tx << 2);
#pragma unroll
        for (int j = 0; j < 4; j++) {
            float v = acc[i][j];
            if (mode == M_ATOMIC) { atomicAdd(&crow[j], v); continue; }
            if (bias) v += bias[bn + (tx << 2) + j];
            if (mode == M_ADD) crow[j] += v;
            else if (mode == M_SKIP) {
                const float* hrow = Hbuf + (size_t)mrow * ldc + bn + (tx << 2);
                crow[j] = gblend * v + hblend * hrow[j];
            } else crow[j] = v;
        }
    }
}

static void launch_gemm(hipStream_t st, bool nt,
                        const float* A, int lda, int aoffz,
                        const float* B, int ldb, int boffz,
                        float* C, int ldc, int coffz,
                        const float* bias, int M, int N, int K,
                        int Z, int splitk, int mode,
                        const float* skipv, const float* Hbuf)
{
    dim3 grid((unsigned)(N >> 6), (unsigned)(M >> 6), (unsigned)(Z * splitk));
    dim3 blk(256);
    if (nt) gemm_kernel<true ><<<grid, blk, 0, st>>>(A, lda, aoffz, B, ldb, boffz, C, ldc, coffz, bias, M, N, K, splitk, mode, skipv, Hbuf);
    else    gemm_kernel<false><<<grid, blk, 0, st>>>(A, lda, aoffz, B, ldb, boffz, C, ldc, coffz, bias, M, N, K, splitk, mode, skipv, Hbuf);
}

// ---------------------------------------------------------------------------
// Per-node relation transform: Y[n, h*64+f] = sum_d X[n, h*64+d] * W[h, d, f]
// (algebraic hoist of the reference's per-edge einsum; gather happens later)
__global__ __launch_bounds__(256) void rel_transform_kernel(
    const float* __restrict__ X, const float* __restrict__ Wrel, float* __restrict__ Y)
{
    __shared__ float Ws[64][64];
    __shared__ float Xs[16][64];
    const int h = blockIdx.y, n0 = blockIdx.x << 4, tid = threadIdx.x;
    const float* Wh = Wrel + h * 4096;
    for (int i = tid; i < 4096; i += 256) Ws[i >> 6][i & 63] = Wh[i];
    for (int i = tid; i < 1024; i += 256) {
        int r = i >> 6, d = i & 63;
        Xs[r][d] = X[(size_t)(n0 + r) * HIDF + (h << 6) + d];
    }
    __syncthreads();
    const int r = tid >> 4, f0 = (tid & 15) << 2;
    float a0 = 0, a1 = 0, a2 = 0, a3 = 0;
#pragma unroll 8
    for (int d = 0; d < 64; d++) {
        float xv = Xs[r][d];
        a0 = fmaf(xv, Ws[d][f0 + 0], a0);
        a1 = fmaf(xv, Ws[d][f0 + 1], a1);
        a2 = fmaf(xv, Ws[d][f0 + 2], a2);
        a3 = fmaf(xv, Ws[d][f0 + 3], a3);
    }
    size_t yb = (size_t)(n0 + r) * HIDF + (h << 6) + f0;
    Y[yb] = a0; Y[yb + 1] = a1; Y[yb + 2] = a2; Y[yb + 3] = a3;
}

// ---------------------------------------------------------------------------
// Edge sorting (counting sort by destination node)
__global__ void count_kernel(const int* __restrict__ dst, int E, int* __restrict__ cnt)
{
    int i = blockIdx.x * 256 + threadIdx.x;
    if (i < E) atomicAdd(&cnt[dst[i]], 1);
}

// Exclusive scan of cntcur[0..N) -> off[0..N]; also rewrites cntcur as running
// cursors (cntcur may alias the input counts; each thread touches only its own
// 16-slot range, reads before any writes, phases separated by barriers).
__global__ __launch_bounds__(256) void scan_kernel(int* __restrict__ cntcur, int N, int* __restrict__ off)
{
    __shared__ int sums[256];
    const int tid = threadIdx.x;
    const int base = tid * 16;
    int vals[16];
    int s = 0;
#pragma unroll
    for (int j = 0; j < 16; j++) {
        int idx = base + j;
        int c = (idx < N) ? cntcur[idx] : 0;
        vals[j] = s; s += c;
    }
    sums[tid] = s;
    __syncthreads();
    for (int d = 1; d < 256; d <<= 1) {
        int v = (tid >= d) ? sums[tid - d] : 0;
        __syncthreads();
        sums[tid] += v;
        __syncthreads();
    }
    int prefix = (tid > 0) ? sums[tid - 1] : 0;
#pragma unroll
    for (int j = 0; j < 16; j++) {
        int idx = base + j;
        if (idx < N) { int v = prefix + vals[j]; off[idx] = v; cntcur[idx] = v; }
    }
    if (tid == 255) off[N] = sums[255];
}

__global__ void scatter_kernel(const int* __restrict__ src, const int* __restrict__ dst, int E,
                               int* __restrict__ cur, int* __restrict__ esrc,
                               int* __restrict__ eflag, int flag)
{
    int i = blockIdx.x * 256 + threadIdx.x;
    if (i < E) {
        int slot = atomicAdd(&cur[dst[i]], 1);
        esrc[slot] = src[i];
        eflag[slot] = flag;
    }
}

// ---------------------------------------------------------------------------
// HGT edge attention with online segment softmax.
// One block per dst node; 4 waves = 4 heads; lane d holds dim d.
// flag 0 -> (Kta,Vta,p_rel[ra]); flag 1 -> (Ktb,Vtb,p_rel[rb]).
__global__ __launch_bounds__(256) void edge_attn_kernel(
    const float* __restrict__ Q, const int* __restrict__ off,
    const int* __restrict__ esrc, const int* __restrict__ eflag,
    const float* __restrict__ Kta, const float* __restrict__ Vta,
    const float* __restrict__ Ktb, const float* __restrict__ Vtb,
    const float* __restrict__ prel, int ra, int rb,
    float* __restrict__ agg)
{
    const int dstn = blockIdx.x;
    const int tid = threadIdx.x, lane = tid & 63, h = tid >> 6;
    const float qv = Q[(size_t)dstn * HIDF + (h << 6) + lane];
    const float pa = prel[ra * NHEAD + h] * ATT_SCALE;
    const float pb = (rb >= 0) ? prel[rb * NHEAD + h] * ATT_SCALE : 0.f;
    const int i0 = off[dstn], i1 = off[dstn + 1];
    float m = -INFINITY, lsum = 0.f, acc = 0.f;
    for (int i = i0; i < i1; i++) {
        const int s = esrc[i], fb = eflag[i];
        const float* Kt = fb ? Ktb : Kta;
        const float* Vt = fb ? Vtb : Vta;
        const size_t base = (size_t)s * HIDF + (h << 6) + lane;
        float dot = qv * Kt[base];
#pragma unroll
        for (int o = 32; o; o >>= 1) dot += __shfl_xor(dot, o);
        const float a = dot * (fb ? pb : pa);
        const float mn = fmaxf(m, a);
        const float sc = expf(m - mn);     // 0 when m == -inf (first edge)
        const float wv = expf(a - mn);
        const float vvv = Vt[base];
        lsum = lsum * sc + wv;
        acc = acc * sc + wv * vvv;
        m = mn;
    }
    agg[(size_t)dstn * HIDF + (h << 6) + lane] = (lsum > 0.f) ? acc / lsum : 0.f;
}

// ---------------------------------------------------------------------------
__global__ void gelu_kernel(float* __restrict__ x, int n)
{
    int i = blockIdx.x * 256 + threadIdx.x;
    if (i < n) x[i] = gelu_exact(x[i]);
}

// Row softmax over 2048 keys; applies ATT_SCALE before max-subtraction.
// S layout: [head][chRows][2048]; grid = (chRows, 4), 256 threads.
__global__ __launch_bounds__(256) void softmax_kernel(float* __restrict__ S, int chRows)
{
    __shared__ float t4[4];
    const int row = blockIdx.x, head = blockIdx.y;
    float* p = S + ((size_t)head * chRows + row) * 2048;
    const int tid = threadIdx.x, lane = tid & 63, w = tid >> 6;
    float x[8];
    float m = -INFINITY;
#pragma unroll
    for (int j = 0; j < 8; j++) { x[j] = p[tid + (j << 8)] * ATT_SCALE; m = fmaxf(m, x[j]); }
#pragma unroll
    for (int o = 32; o; o >>= 1) m = fmaxf(m, __shfl_xor(m, o));
    if (lane == 0) t4[w] = m;
    __syncthreads();
    m = fmaxf(fmaxf(t4[0], t4[1]), fmaxf(t4[2], t4[3]));
    __syncthreads();
    float s = 0.f;
#pragma unroll
    for (int j = 0; j < 8; j++) { x[j] = expf(x[j] - m); s += x[j]; }
#pragma unroll
    for (int o = 32; o; o >>= 1) s += __shfl_xor(s, o);
    if (lane == 0) t4[w] = s;
    __syncthreads();
    s = t4[0] + t4[1] + t4[2] + t4[3];
    const float inv = 1.f / s;
#pragma unroll
    for (int j = 0; j < 8; j++) p[tid + (j << 8)] = x[j] * inv;
}

// Fused residual + LayerNorm + exact GELU (in-place update of h).
__global__ __launch_bounds__(256) void ln_gelu_kernel(
    float* __restrict__ h, const float* __restrict__ hg,
    const float* __restrict__ g, const float* __restrict__ b)
{
    __shared__ float t4[4];
    const int row = blockIdx.x, tid = threadIdx.x, lane = tid & 63, w = tid >> 6;
    const size_t idx = (size_t)row * HIDF + tid;
    const float x = h[idx] + hg[idx];
    float v = x;
#pragma unroll
    for (int o = 32; o; o >>= 1) v += __shfl_xor(v, o);
    if (lane == 0) t4[w] = v;
    __syncthreads();
    const float mean = (t4[0] + t4[1] + t4[2] + t4[3]) * (1.f / 256.f);
    __syncthreads();
    const float d = x - mean;
    v = d * d;
#pragma unroll
    for (int o = 32; o; o >>= 1) v += __shfl_xor(v, o);
    if (lane == 0) t4[w] = v;
    __syncthreads();
    const float var = (t4[0] + t4[1] + t4[2] + t4[3]) * (1.f / 256.f);
    const float y = d * rsqrtf(var + 1e-5f) * g[tid] + b[tid];
    h[idx] = gelu_exact(y);
}

// ---------------------------------------------------------------------------
extern "C" void kernel_launch(void* const* d_in, const int* in_sizes, int n_in,
                              void* d_out, int out_size, void* d_ws, size_t ws_size,
                              hipStream_t stream)
{
    (void)in_sizes; (void)n_in; (void)out_size; (void)ws_size;
    const float* x_p   = (const float*)d_in[0];
    const float* x_g   = (const float*)d_in[1];
    const float* x_m   = (const float*)d_in[2];
    const int*  src_pg = (const int*)d_in[3];
    const int*  dst_pg = (const int*)d_in[4];
    const int*  src_gp = (const int*)d_in[5];
    const int*  dst_gp = (const int*)d_in[6];
    const int*  src_pm = (const int*)d_in[7];
    const int*  dst_pm = (const int*)d_in[8];
    const int*  src_mp = (const int*)d_in[9];
    const int*  dst_mp = (const int*)d_in[10];
    const float* Win_p = (const float*)d_in[11];
    const float* bin_p = (const float*)d_in[12];
    const float* Win_g = (const float*)d_in[13];
    const float* bin_g = (const float*)d_in[14];
    const float* Win_m = (const float*)d_in[15];
    const float* bin_m = (const float*)d_in[16];
    const float* kw    = (const float*)d_in[17];
    const float* qw    = (const float*)d_in[18];
    const float* vw    = (const float*)d_in[19];
    const float* aw    = (const float*)d_in[20];
    const float* kb    = (const float*)d_in[21];
    const float* qb    = (const float*)d_in[22];
    const float* vb    = (const float*)d_in[23];
    const float* ab    = (const float*)d_in[24];
    const float* skip  = (const float*)d_in[25];
    const float* a_rel = (const float*)d_in[26];
    const float* m_rel = (const float*)d_in[27];
    const float* p_rel = (const float*)d_in[28];
    const float* ca_qw = (const float*)d_in[29];
    const float* ca_kw = (const float*)d_in[30];
    const float* ca_vw = (const float*)d_in[31];
    const float* ca_ow = (const float*)d_in[32];
    const float* ca_qb = (const float*)d_in[33];
    const float* ca_kb = (const float*)d_in[34];
    const float* ca_vb = (const float*)d_in[35];
    const float* ca_ob = (const float*)d_in[36];
    const float* ln_g  = (const float*)d_in[37];
    const float* ln_b  = (const float*)d_in[38];
    const float* outw  = (const float*)d_in[39];
    const float* outb  = (const float*)d_in[40];
    float* dout = (float*)d_out;

    // ---- workspace carve-up (~88 MB total) ----
    float* Wp = (float*)d_ws;
    size_t cursz = 0;
    auto alloc = [&](size_t n) -> float* {
        float* p = Wp + cursz; cursz += (n + 63) & ~(size_t)63; return p;
    };
    float* h0  = alloc((size_t)N0 * HIDF);
    float* h1  = alloc((size_t)N1 * HIDF);
    float* h2  = alloc((size_t)N2 * HIDF);
    float* hg0 = alloc((size_t)N0 * HIDF);
    float* hg1 = alloc((size_t)N1 * HIDF);
    float* hg2 = alloc((size_t)N2 * HIDF);
    float* Q0  = alloc((size_t)N0 * HIDF);
    float* Q1  = alloc((size_t)N1 * HIDF);
    float* Q2  = alloc((size_t)N2 * HIDF);
    float* Kb0 = alloc((size_t)N0 * HIDF);
    float* Kb1 = alloc((size_t)N1 * HIDF);
    float* Kb2 = alloc((size_t)N2 * HIDF);
    float* Vb0 = alloc((size_t)N0 * HIDF);
    float* Vb1 = alloc((size_t)N1 * HIDF);
    float* Vb2 = alloc((size_t)N2 * HIDF);
    // pool: K~/V~/agg during HGT phase, re-used as the cross-attn score buffer
    float* pool = alloc((size_t)4 * CH * 2048);   // 8.39 M floats (>= Kt+Vt+agg)
    float* Kt0 = pool;
    float* Kt1 = Kt0 + (size_t)N0 * HIDF;
    float* Kt2 = Kt1 + (size_t)N1 * HIDF;
    float* Kt3 = Kt2 + (size_t)N0 * HIDF;
    float* Vt0 = Kt3 + (size_t)N2 * HIDF;
    float* Vt1 = Vt0 + (size_t)N0 * HIDF;
    float* Vt2 = Vt1 + (size_t)N1 * HIDF;
    float* Vt3 = Vt2 + (size_t)N0 * HIDF;
    float* agg0 = Vt3 + (size_t)N2 * HIDF;
    float* agg1 = agg0 + (size_t)N0 * HIDF;
    float* agg2 = agg1 + (size_t)N1 * HIDF;
    float* Sbuf = pool;
    // cross-attn q/k/v/o alias the (already consumed) K/V projection buffers
    float* caq = Kb1; float* cak = Kb0; float* cav = Vb0; float* cao = Vb1;
    int* esrc0  = (int*)alloc(E_GP + E_MP);
    int* eflag0 = (int*)alloc(E_GP + E_MP);
    int* esrc1  = (int*)alloc(E_PG);
    int* eflag1 = (int*)alloc(E_PG);
    int* esrc2  = (int*)alloc(E_PM);
    int* eflag2 = (int*)alloc(E_PM);
    int* off0 = (int*)alloc(N0 + 1); int* cur0 = (int*)alloc(N0);
    int* off1 = (int*)alloc(N1 + 1); int* cur1 = (int*)alloc(N1);
    int* off2 = (int*)alloc(N2 + 1); int* cur2 = (int*)alloc(N2);

    // ---- counting-sort edges by destination (per dst type) ----
    hipMemsetAsync(cur0, 0, N0 * sizeof(int), stream);
    count_kernel<<<(E_GP + 255) / 256, 256, 0, stream>>>(dst_gp, E_GP, cur0);
    count_kernel<<<(E_MP + 255) / 256, 256, 0, stream>>>(dst_mp, E_MP, cur0);
    scan_kernel<<<1, 256, 0, stream>>>(cur0, N0, off0);
    scatter_kernel<<<(E_GP + 255) / 256, 256, 0, stream>>>(src_gp, dst_gp, E_GP, cur0, esrc0, eflag0, 0);
    scatter_kernel<<<(E_MP + 255) / 256, 256, 0, stream>>>(src_mp, dst_mp, E_MP, cur0, esrc0, eflag0, 1);

    hipMemsetAsync(cur1, 0, N1 * sizeof(int), stream);
    count_kernel<<<(E_PG + 255) / 256, 256, 0, stream>>>(dst_pg, E_PG, cur1);
    scan_kernel<<<1, 256, 0, stream>>>(cur1, N1, off1);
    scatter_kernel<<<(E_PG + 255) / 256, 256, 0, stream>>>(src_pg, dst_pg, E_PG, cur1, esrc1, eflag1, 0);

    hipMemsetAsync(cur2, 0, N2 * sizeof(int), stream);
    count_kernel<<<(E_PM + 255) / 256, 256, 0, stream>>>(dst_pm, E_PM, cur2);
    scan_kernel<<<1, 256, 0, stream>>>(cur2, N2, off2);
    scatter_kernel<<<(E_PM + 255) / 256, 256, 0, stream>>>(src_pm, dst_pm, E_PM, cur2, esrc2, eflag2, 0);

    // ---- input projections ----
    launch_gemm(stream, false, x_p, 512, 0, Win_p, HIDF, 0, h0, HIDF, 0, bin_p, N0, HIDF, 512, 1, 1, M_STORE, nullptr, nullptr);
    launch_gemm(stream, false, x_g, 768, 0, Win_g, HIDF, 0, h1, HIDF, 0, bin_g, N1, HIDF, 768, 1, 1, M_STORE, nullptr, nullptr);
    launch_gemm(stream, false, x_m, 384, 0, Win_m, HIDF, 0, h2, HIDF, 0, bin_m, N2, HIDF, 384, 1, 1, M_STORE, nullptr, nullptr);

    float* hptr[3]  = { h0, h1, h2 };
    float* hgptr[3] = { hg0, hg1, hg2 };
    float* Qptr[3]  = { Q0, Q1, Q2 };
    float* Kbp[3]   = { Kb0, Kb1, Kb2 };
    float* Vbp[3]   = { Vb0, Vb1, Vb2 };
    float* aggp[3]  = { agg0, agg1, agg2 };
    const int Ns[3] = { N0, N1, N2 };

    for (int l = 0; l < 2; l++) {
        // K/Q/V projections per node type
        for (int t = 0; t < 3; t++) {
            const size_t wo = (size_t)(l * 3 + t) * HIDF * HIDF;
            const size_t bo = (size_t)(l * 3 + t) * HIDF;
            launch_gemm(stream, false, hptr[t], HIDF, 0, qw + wo, HIDF, 0, Qptr[t], HIDF, 0, qb + bo, Ns[t], HIDF, HIDF, 1, 1, M_STORE, nullptr, nullptr);
            launch_gemm(stream, false, hptr[t], HIDF, 0, kw + wo, HIDF, 0, Kbp[t], HIDF, 0, kb + bo, Ns[t], HIDF, HIDF, 1, 1, M_STORE, nullptr, nullptr);
            launch_gemm(stream, false, hptr[t], HIDF, 0, vw + wo, HIDF, 0, Vbp[t], HIDF, 0, vb + bo, Ns[t], HIDF, HIDF, 1, 1, M_STORE, nullptr, nullptr);
        }
        // per-relation node transforms (K~ = K@a_rel, V~ = V@m_rel); src types: r0:p r1:g r2:p r3:m
        const float* ar = a_rel + (size_t)l * 4 * 16384;
        const float* mr = m_rel + (size_t)l * 4 * 16384;
        rel_transform_kernel<<<dim3(N0 / 16, NHEAD), 256, 0, stream>>>(Kb0, ar + 0 * 16384, Kt0);
        rel_transform_kernel<<<dim3(N0 / 16, NHEAD), 256, 0, stream>>>(Vb0, mr + 0 * 16384, Vt0);
        rel_transform_kernel<<<dim3(N1 / 16, NHEAD), 256, 0, stream>>>(Kb1, ar + 1 * 16384, Kt1);
        rel_transform_kernel<<<dim3(N1 / 16, NHEAD), 256, 0, stream>>>(Vb1, mr + 1 * 16384, Vt1);
        rel_transform_kernel<<<dim3(N0 / 16, NHEAD), 256, 0, stream>>>(Kb0, ar + 2 * 16384, Kt2);
        rel_transform_kernel<<<dim3(N0 / 16, NHEAD), 256, 0, stream>>>(Vb0, mr + 2 * 16384, Vt2);
        rel_transform_kernel<<<dim3(N2 / 16, NHEAD), 256, 0, stream>>>(Kb2, ar + 3 * 16384, Kt3);
        rel_transform_kernel<<<dim3(N2 / 16, NHEAD), 256, 0, stream>>>(Vb2, mr + 3 * 16384, Vt3);

        // segment-softmax edge attention
        const float* prl = p_rel + (size_t)l * 16;
        edge_attn_kernel<<<N0, 256, 0, stream>>>(Q0, off0, esrc0, eflag0, Kt1, Vt1, Kt3, Vt3, prl, 1, 3, agg0);
        edge_attn_kernel<<<N1, 256, 0, stream>>>(Q1, off1, esrc1, eflag1, Kt0, Vt0, Kt0, Vt0, prl, 0, -1, agg1);
        edge_attn_kernel<<<N2, 256, 0, stream>>>(Q2, off2, esrc2, eflag2, Kt2, Vt2, Kt2, Vt2, prl, 2, -1, agg2);

        // hg = sigmoid(skip) * (gelu(agg) @ aw + ab) + (1-sigmoid(skip)) * h
        for (int t = 0; t < 3; t++) {
            gelu_kernel<<<(Ns[t] * HIDF + 255) / 256, 256, 0, stream>>>(aggp[t], Ns[t] * HIDF);
            const size_t wo = (size_t)(l * 3 + t) * HIDF * HIDF;
            const size_t bo = (size_t)(l * 3 + t) * HIDF;
            launch_gemm(stream, false, aggp[t], HIDF, 0, aw + wo, HIDF, 0, hgptr[t], HIDF, 0, ab + bo,
                        Ns[t], HIDF, HIDF, 1, 1, M_SKIP, skip + l * 3 + t, hptr[t]);
        }

        // cross attention: types 1,2 attend to participants (h0)
        for (int t = 1; t <= 2; t++) {
            const int c = t - 1, Nq = Ns[t];
            launch_gemm(stream, false, hptr[t], HIDF, 0, ca_qw + (size_t)c * 65536, HIDF, 0, caq, HIDF, 0, ca_qb + c * HIDF, Nq, HIDF, HIDF, 1, 1, M_STORE, nullptr, nullptr);
            launch_gemm(stream, false, h0, HIDF, 0, ca_kw + (size_t)c * 65536, HIDF, 0, cak, HIDF, 0, ca_kb + c * HIDF, N0, HIDF, HIDF, 1, 1, M_STORE, nullptr, nullptr);
            launch_gemm(stream, false, h0, HIDF, 0, ca_vw + (size_t)c * 65536, HIDF, 0, cav, HIDF, 0, ca_vb + c * HIDF, N0, HIDF, HIDF, 1, 1, M_STORE, nullptr, nullptr);
            hipMemsetAsync(cao, 0, (size_t)Nq * HIDF * sizeof(float), stream);
            for (int r0 = 0; r0 < Nq; r0 += CH) {
                // S[h] = q_chunk @ k^T  (head-batched NT GEMM)
                launch_gemm(stream, true, caq + (size_t)r0 * HIDF, HIDF, HDIM,
                            cak, HIDF, HDIM, Sbuf, 2048, CH * 2048, nullptr,
                            CH, 2048, HDIM, NHEAD, 1, M_STORE, nullptr, nullptr);
                softmax_kernel<<<dim3(CH, NHEAD), 256, 0, stream>>>(Sbuf, CH);
                // o_chunk[h] += P @ v  (split-K atomic; cao zeroed above)
                launch_gemm(stream, false, Sbuf, 2048, CH * 2048, cav, HIDF, HDIM,
                            cao + (size_t)r0 * HIDF, HIDF, HDIM, nullptr,
                            CH, HDIM, 2048, NHEAD, 8, M_ATOMIC, nullptr, nullptr);
            }
            launch_gemm(stream, false, cao, HIDF, 0, ca_ow + (size_t)c * 65536, HIDF, 0,
                        hgptr[t], HIDF, 0, ca_ob + c * HIDF, Nq, HIDF, HIDF, 1, 1, M_ADD, nullptr, nullptr);
        }

        // h = gelu(LN(h + hg))
        for (int t = 0; t < 3; t++)
            ln_gelu_kernel<<<Ns[t], 256, 0, stream>>>(hptr[t], hgptr[t], ln_g + t * HIDF, ln_b + t * HIDF);
    }

    // ---- output projections (concatenated rows) ----
    launch_gemm(stream, false, h0, HIDF, 0, outw + 0,      OUTF, 0, dout,                          OUTF, 0, outb,        N0, OUTF, HIDF, 1, 1, M_STORE, nullptr, nullptr);
    launch_gemm(stream, false, h1, HIDF, 0, outw + 32768,  OUTF, 0, dout + (size_t)N0 * OUTF,      OUTF, 0, outb + 128,  N1, OUTF, HIDF, 1, 1, M_STORE, nullptr, nullptr);
    launch_gemm(stream, false, h2, HIDF, 0, outw + 65536,  OUTF, 0, dout + (size_t)(N0 + N1) * OUTF, OUTF, 0, outb + 256, N2, OUTF, HIDF, 1, 1, M_STORE, nullptr, nullptr);
}

// Round 2
// 2203.529 us; speedup vs baseline: 1.4190x; 1.4190x over previous
//
#include <hip/hip_runtime.h>
#include <math.h>
#include <stdint.h>
#include <stddef.h>

// ---------------------------------------------------------------------------
// Heterogeneous Graph Transformer + cross-attention, fp32.
static constexpr int NHEAD = 4;
static constexpr int HDIM  = 64;
static constexpr int HIDF  = 256;   // NHEAD*HDIM
static constexpr int OUTF  = 128;
static constexpr int N0 = 2048, N1 = 4096, N2 = 3072;   // participant, gene, metabolite
static constexpr int E_PG = 250000, E_GP = 250000, E_PM = 200000, E_MP = 200000;
static constexpr float ATT_SCALE = 0.125f;              // 1/sqrt(64)

enum { M_STORE = 0, M_ADD = 1, M_SKIP = 2, M_ATOMIC = 3 };

__device__ __forceinline__ float gelu_exact(float x) {
    return 0.5f * x * (1.0f + erff(x * 0.7071067811865476f));
}

// ---------------------------------------------------------------------------
// Generic tiled fp32 GEMM (non-batched variant, used for irregular shapes).
//   NT=false: B is [K,N] (ldb).  NT=true: B is [N,K] (ldb) -> C = A @ B^T.
// Head-batched via blockIdx.z: per-z element offsets aoffz/boffz/coffz.
// splitk>1 (mode must be M_ATOMIC): z = head*splitk + kslice.
template <bool NT>
__global__ __launch_bounds__(256) void gemm_kernel(
    const float* __restrict__ A, int lda, int aoffz,
    const float* __restrict__ B, int ldb, int boffz,
    float* __restrict__ C, int ldc, int coffz,
    const float* __restrict__ bias,
    int M, int N, int K, int splitk, int mode)
{
    const int z = blockIdx.z;
    const int head = z / splitk, ks = z - head * splitk;
    A += (size_t)head * aoffz;
    B += (size_t)head * boffz;
    C += (size_t)head * coffz;
    const int klen = K / splitk;
    const int kbeg = ks * klen, kend = kbeg + klen;

    __shared__ float As[16][64];
    __shared__ float Bs[16][64];
    const int tid = threadIdx.x;
    const int tx = tid & 15, ty = tid >> 4;
    const int bm = blockIdx.y << 6, bn = blockIdx.x << 6;
    const int alr = tid >> 2, alc = (tid & 3) << 2;
    const int blr = tid >> 4, blc = (tid & 15) << 2;

    float acc[4][4] = {};

    for (int k0 = kbeg; k0 < kend; k0 += 16) {
        float4 av = *(const float4*)(A + (size_t)(bm + alr) * lda + k0 + alc);
        As[alc + 0][alr] = av.x; As[alc + 1][alr] = av.y;
        As[alc + 2][alr] = av.z; As[alc + 3][alr] = av.w;
        if (!NT) {
            float4 bv = *(const float4*)(B + (size_t)(k0 + blr) * ldb + bn + blc);
            *(float4*)&Bs[blr][blc] = bv;
        } else {
            float4 bv = *(const float4*)(B + (size_t)(bn + alr) * ldb + k0 + alc);
            Bs[alc + 0][alr] = bv.x; Bs[alc + 1][alr] = bv.y;
            Bs[alc + 2][alr] = bv.z; Bs[alc + 3][alr] = bv.w;
        }
        __syncthreads();
#pragma unroll
        for (int kk = 0; kk < 16; kk++) {
            const float4 a4 = *(const float4*)&As[kk][ty << 2];
            const float4 b4 = *(const float4*)&Bs[kk][tx << 2];
            acc[0][0] = fmaf(a4.x, b4.x, acc[0][0]);
            acc[0][1] = fmaf(a4.x, b4.y, acc[0][1]);
            acc[0][2] = fmaf(a4.x, b4.z, acc[0][2]);
            acc[0][3] = fmaf(a4.x, b4.w, acc[0][3]);
            acc[1][0] = fmaf(a4.y, b4.x, acc[1][0]);
            acc[1][1] = fmaf(a4.y, b4.y, acc[1][1]);
            acc[1][2] = fmaf(a4.y, b4.z, acc[1][2]);
            acc[1][3] = fmaf(a4.y, b4.w, acc[1][3]);
            acc[2][0] = fmaf(a4.z, b4.x, acc[2][0]);
            acc[2][1] = fmaf(a4.z, b4.y, acc[2][1]);
            acc[2][2] = fmaf(a4.z, b4.z, acc[2][2]);
            acc[2][3] = fmaf(a4.z, b4.w, acc[2][3]);
            acc[3][0] = fmaf(a4.w, b4.x, acc[3][0]);
            acc[3][1] = fmaf(a4.w, b4.y, acc[3][1]);
            acc[3][2] = fmaf(a4.w, b4.z, acc[3][2]);
            acc[3][3] = fmaf(a4.w, b4.w, acc[3][3]);
        }
        __syncthreads();
    }

#pragma unroll
    for (int i = 0; i < 4; i++) {
        const int mrow = bm + (ty << 2) + i;
        float* crow = C + (size_t)mrow * ldc + bn + (tx << 2);
#pragma unroll
        for (int j = 0; j < 4; j++) {
            float v = acc[i][j];
            if (mode == M_ATOMIC) { atomicAdd(&crow[j], v); continue; }
            if (bias) v += bias[bn + (tx << 2) + j];
            if (mode == M_ADD) crow[j] += v;
            else crow[j] = v;
        }
    }
}

static void launch_gemm(hipStream_t st, bool nt,
                        const float* A, int lda, int aoffz,
                        const float* B, int ldb, int boffz,
                        float* C, int ldc, int coffz,
                        const float* bias, int M, int N, int K,
                        int Z, int splitk, int mode)
{
    dim3 grid((unsigned)(N >> 6), (unsigned)(M >> 6), (unsigned)(Z * splitk));
    dim3 blk(256);
    if (nt) gemm_kernel<true ><<<grid, blk, 0, st>>>(A, lda, aoffz, B, ldb, boffz, C, ldc, coffz, bias, M, N, K, splitk, mode);
    else    gemm_kernel<false><<<grid, blk, 0, st>>>(A, lda, aoffz, B, ldb, boffz, C, ldc, coffz, bias, M, N, K, splitk, mode);
}

// ---------------------------------------------------------------------------
// Descriptor-batched NN GEMM: z picks a descriptor. A is [M,K] row-major
// (lda=K), B is [K,N] (ldb=N), C is [M,N] (ldc=N). MODE: STORE or SKIP.
struct GemmDesc {
    const float* A; const float* B; float* C;
    const float* bias; const float* skipv; const float* H;
    int M;
};
template <int NZ> struct GemmDescArr { GemmDesc d[NZ]; };

template <int NZ, int MODE>
__global__ __launch_bounds__(256) void gemm_nn_batched(GemmDescArr<NZ> P, int N, int K)
{
    const GemmDesc g = P.d[blockIdx.z];
    const int bm = blockIdx.y << 6;
    if (bm >= g.M) return;
    const int bn = blockIdx.x << 6;

    __shared__ float As[16][64];
    __shared__ float Bs[16][64];
    const int tid = threadIdx.x;
    const int tx = tid & 15, ty = tid >> 4;
    const int alr = tid >> 2, alc = (tid & 3) << 2;
    const int blr = tid >> 4, blc = (tid & 15) << 2;

    float acc[4][4] = {};
    for (int k0 = 0; k0 < K; k0 += 16) {
        float4 av = *(const float4*)(g.A + (size_t)(bm + alr) * K + k0 + alc);
        As[alc + 0][alr] = av.x; As[alc + 1][alr] = av.y;
        As[alc + 2][alr] = av.z; As[alc + 3][alr] = av.w;
        float4 bv = *(const float4*)(g.B + (size_t)(k0 + blr) * N + bn + blc);
        *(float4*)&Bs[blr][blc] = bv;
        __syncthreads();
#pragma unroll
        for (int kk = 0; kk < 16; kk++) {
            const float4 a4 = *(const float4*)&As[kk][ty << 2];
            const float4 b4 = *(const float4*)&Bs[kk][tx << 2];
            acc[0][0] = fmaf(a4.x, b4.x, acc[0][0]);
            acc[0][1] = fmaf(a4.x, b4.y, acc[0][1]);
            acc[0][2] = fmaf(a4.x, b4.z, acc[0][2]);
            acc[0][3] = fmaf(a4.x, b4.w, acc[0][3]);
            acc[1][0] = fmaf(a4.y, b4.x, acc[1][0]);
            acc[1][1] = fmaf(a4.y, b4.y, acc[1][1]);
            acc[1][2] = fmaf(a4.y, b4.z, acc[1][2]);
            acc[1][3] = fmaf(a4.y, b4.w, acc[1][3]);
            acc[2][0] = fmaf(a4.z, b4.x, acc[2][0]);
            acc[2][1] = fmaf(a4.z, b4.y, acc[2][1]);
            acc[2][2] = fmaf(a4.z, b4.z, acc[2][2]);
            acc[2][3] = fmaf(a4.z, b4.w, acc[2][3]);
            acc[3][0] = fmaf(a4.w, b4.x, acc[3][0]);
            acc[3][1] = fmaf(a4.w, b4.y, acc[3][1]);
            acc[3][2] = fmaf(a4.w, b4.z, acc[3][2]);
            acc[3][3] = fmaf(a4.w, b4.w, acc[3][3]);
        }
        __syncthreads();
    }

    float gblend = 0.f, hblend = 0.f;
    if (MODE == M_SKIP) {
        const float sv = g.skipv[0];
        gblend = 1.f / (1.f + expf(-sv));
        hblend = 1.f - gblend;
    }
#pragma unroll
    for (int i = 0; i < 4; i++) {
        const int mrow = bm + (ty << 2) + i;
        float* crow = g.C + (size_t)mrow * N + bn + (tx << 2);
#pragma unroll
        for (int j = 0; j < 4; j++) {
            float v = acc[i][j] + g.bias[bn + (tx << 2) + j];
            if (MODE == M_SKIP) {
                const float* hrow = g.H + (size_t)mrow * N + bn + (tx << 2);
                crow[j] = gblend * v + hblend * hrow[j];
            } else crow[j] = v;
        }
    }
}

// ---------------------------------------------------------------------------
// Per-node relation transform, batched over 8 (relation, K/V) combos:
// Y[n, h*64+f] = sum_d X[n, h*64+d] * W[h, d, f]
struct RelDesc { const float* X; const float* W; float* Y; int rows; };
struct RelDescArr { RelDesc d[8]; };

__global__ __launch_bounds__(256) void rel_transform_batched(RelDescArr P)
{
    const RelDesc g = P.d[blockIdx.z];
    const int n0 = blockIdx.x << 4;
    if (n0 >= g.rows) return;
    __shared__ float Ws[64][64];
    __shared__ float Xs[16][64];
    const int h = blockIdx.y, tid = threadIdx.x;
    const float* Wh = g.W + h * 4096;
    for (int i = tid; i < 4096; i += 256) Ws[i >> 6][i & 63] = Wh[i];
    for (int i = tid; i < 1024; i += 256) {
        int r = i >> 6, d = i & 63;
        Xs[r][d] = g.X[(size_t)(n0 + r) * HIDF + (h << 6) + d];
    }
    __syncthreads();
    const int r = tid >> 4, f0 = (tid & 15) << 2;
    float a0 = 0, a1 = 0, a2 = 0, a3 = 0;
#pragma unroll 8
    for (int d = 0; d < 64; d++) {
        float xv = Xs[r][d];
        a0 = fmaf(xv, Ws[d][f0 + 0], a0);
        a1 = fmaf(xv, Ws[d][f0 + 1], a1);
        a2 = fmaf(xv, Ws[d][f0 + 2], a2);
        a3 = fmaf(xv, Ws[d][f0 + 3], a3);
    }
    size_t yb = (size_t)(n0 + r) * HIDF + (h << 6) + f0;
    g.Y[yb] = a0; g.Y[yb + 1] = a1; g.Y[yb + 2] = a2; g.Y[yb + 3] = a3;
}

// ---------------------------------------------------------------------------
// Edge sorting (counting sort by destination node)
__global__ void count_kernel(const int* __restrict__ dst, int E, int* __restrict__ cnt)
{
    int i = blockIdx.x * 256 + threadIdx.x;
    if (i < E) atomicAdd(&cnt[dst[i]], 1);
}

__global__ __launch_bounds__(256) void scan_kernel(int* __restrict__ cntcur, int N, int* __restrict__ off)
{
    __shared__ int sums[256];
    const int tid = threadIdx.x;
    const int base = tid * 16;
    int vals[16];
    int s = 0;
#pragma unroll
    for (int j = 0; j < 16; j++) {
        int idx = base + j;
        int c = (idx < N) ? cntcur[idx] : 0;
        vals[j] = s; s += c;
    }
    sums[tid] = s;
    __syncthreads();
    for (int d = 1; d < 256; d <<= 1) {
        int v = (tid >= d) ? sums[tid - d] : 0;
        __syncthreads();
        sums[tid] += v;
        __syncthreads();
    }
    int prefix = (tid > 0) ? sums[tid - 1] : 0;
#pragma unroll
    for (int j = 0; j < 16; j++) {
        int idx = base + j;
        if (idx < N) { int v = prefix + vals[j]; off[idx] = v; cntcur[idx] = v; }
    }
    if (tid == 255) off[N] = sums[255];
}

__global__ void scatter_kernel(const int* __restrict__ src, const int* __restrict__ dst, int E,
                               int* __restrict__ cur, int* __restrict__ esrc,
                               int* __restrict__ eflag, int flag)
{
    int i = blockIdx.x * 256 + threadIdx.x;
    if (i < E) {
        int slot = atomicAdd(&cur[dst[i]], 1);
        esrc[slot] = src[i];
        eflag[slot] = flag;
    }
}

// ---------------------------------------------------------------------------
// HGT edge attention, chunked online segment softmax.
// One block per dst node; wave h = head h. Edges processed 64 at a time:
//  phase 1: lane = edge, full 64-dim dot (Q broadcast from LDS, K~ gathered)
//  phase 2: ONE shuffle max + ONE shuffle sum per 64 edges (amortized 64x)
//  phase 3: lane = dim, weights broadcast from LDS, V~ gathers coalesced.
__global__ __launch_bounds__(256) void edge_attn_kernel(
    const float* __restrict__ Q, const int* __restrict__ off,
    const int* __restrict__ esrc, const int* __restrict__ eflag,
    const float* __restrict__ Kta, const float* __restrict__ Vta,
    const float* __restrict__ Ktb, const float* __restrict__ Vtb,
    const float* __restrict__ prel, int ra, int rb,
    float* __restrict__ agg)
{
    __shared__ float Qs[NHEAD][HDIM];
    __shared__ float2 WE[NHEAD][64];   // {weight, bitcast(src*2|flag)}
    const int dstn = blockIdx.x;
    const int tid = threadIdx.x, lane = tid & 63, h = tid >> 6;
    Qs[h][lane] = Q[(size_t)dstn * HIDF + (h << 6) + lane];
    __syncthreads();
    const float pa = prel[ra * NHEAD + h] * ATT_SCALE;
    const float pb = (rb >= 0) ? prel[rb * NHEAD + h] * ATT_SCALE : 0.f;
    const int i0 = off[dstn], i1 = off[dstn + 1];
    float m = -INFINITY, lsum = 0.f, acc = 0.f;

    for (int c = i0; c < i1; c += 64) {
        const int e = c + lane;
        float a = -INFINITY;
        int pk = 0;
        if (e < i1) {
            const int s = esrc[e], fb = eflag[e];
            pk = (s << 1) | fb;
            const float* krow = (fb ? Ktb : Kta) + (size_t)s * HIDF + (h << 6);
            float dot = 0.f;
#pragma unroll
            for (int j = 0; j < 16; j++) {
                const float4 kv = *(const float4*)(krow + (j << 2));
                const float4 qv = *(const float4*)&Qs[h][j << 2];
                dot = fmaf(kv.x, qv.x, dot);
                dot = fmaf(kv.y, qv.y, dot);
                dot = fmaf(kv.z, qv.z, dot);
                dot = fmaf(kv.w, qv.w, dot);
            }
            a = dot * (fb ? pb : pa);
        }
        float cm = a;
#pragma unroll
        for (int o = 32; o; o >>= 1) cm = fmaxf(cm, __shfl_xor(cm, o));
        const float mn = fmaxf(m, cm);
        const float scale = (m == -INFINITY) ? 0.f : expf(m - mn);
        const float w = (e < i1) ? expf(a - mn) : 0.f;
        float ws = w;
#pragma unroll
        for (int o = 32; o; o >>= 1) ws += __shfl_xor(ws, o);
        lsum = lsum * scale + ws;
        m = mn;
        WE[h][lane] = make_float2(w, __int_as_float(pk));
        __syncthreads();   // uniform trip count across all 4 waves
        acc *= scale;
        const int nvalid = min(64, i1 - c);
#pragma unroll 4
        for (int e2 = 0; e2 < nvalid; e2++) {
            const float2 we = WE[h][e2];
            const int pk2 = __float_as_int(we.y);
            const float* Vt = (pk2 & 1) ? Vtb : Vta;
            acc = fmaf(we.x, Vt[(size_t)(pk2 >> 1) * HIDF + (h << 6) + lane], acc);
        }
        __syncthreads();
    }
    agg[(size_t)dstn * HIDF + (h << 6) + lane] = (lsum > 0.f) ? acc / lsum : 0.f;
}

// ---------------------------------------------------------------------------
__global__ void gelu4_kernel(float* __restrict__ x, int n4)
{
    int i = blockIdx.x * 256 + threadIdx.x;
    if (i < n4) {
        float4 v = ((float4*)x)[i];
        v.x = gelu_exact(v.x); v.y = gelu_exact(v.y);
        v.z = gelu_exact(v.z); v.w = gelu_exact(v.w);
        ((float4*)x)[i] = v;
    }
}

// Row softmax over 2048 keys; applies ATT_SCALE before max-subtraction.
// S layout: [head][chRows][2048]; grid = (chRows, 4), 256 threads.
__global__ __launch_bounds__(256) void softmax_kernel(float* __restrict__ S, int chRows)
{
    __shared__ float t4[4];
    const int row = blockIdx.x, head = blockIdx.y;
    float* p = S + ((size_t)head * chRows + row) * 2048;
    const int tid = threadIdx.x, lane = tid & 63, w = tid >> 6;
    float x[8];
    float m = -INFINITY;
#pragma unroll
    for (int j = 0; j < 8; j++) { x[j] = p[tid + (j << 8)] * ATT_SCALE; m = fmaxf(m, x[j]); }
#pragma unroll
    for (int o = 32; o; o >>= 1) m = fmaxf(m, __shfl_xor(m, o));
    if (lane == 0) t4[w] = m;
    __syncthreads();
    m = fmaxf(fmaxf(t4[0], t4[1]), fmaxf(t4[2], t4[3]));
    __syncthreads();
    float s = 0.f;
#pragma unroll
    for (int j = 0; j < 8; j++) { x[j] = expf(x[j] - m); s += x[j]; }
#pragma unroll
    for (int o = 32; o; o >>= 1) s += __shfl_xor(s, o);
    if (lane == 0) t4[w] = s;
    __syncthreads();
    s = t4[0] + t4[1] + t4[2] + t4[3];
    const float inv = 1.f / s;
#pragma unroll
    for (int j = 0; j < 8; j++) p[tid + (j << 8)] = x[j] * inv;
}

// Fused residual + LayerNorm + exact GELU (in-place update of h).
__global__ __launch_bounds__(256) void ln_gelu_kernel(
    float* __restrict__ h, const float* __restrict__ hg,
    const float* __restrict__ g, const float* __restrict__ b)
{
    __shared__ float t4[4];
    const int row = blockIdx.x, tid = threadIdx.x, lane = tid & 63, w = tid >> 6;
    const size_t idx = (size_t)row * HIDF + tid;
    const float x = h[idx] + hg[idx];
    float v = x;
#pragma unroll
    for (int o = 32; o; o >>= 1) v += __shfl_xor(v, o);
    if (lane == 0) t4[w] = v;
    __syncthreads();
    const float mean = (t4[0] + t4[1] + t4[2] + t4[3]) * (1.f / 256.f);
    __syncthreads();
    const float d = x - mean;
    v = d * d;
#pragma unroll
    for (int o = 32; o; o >>= 1) v += __shfl_xor(v, o);
    if (lane == 0) t4[w] = v;
    __syncthreads();
    const float var = (t4[0] + t4[1] + t4[2] + t4[3]) * (1.f / 256.f);
    const float y = d * rsqrtf(var + 1e-5f) * g[tid] + b[tid];
    h[idx] = gelu_exact(y);
}

// ---------------------------------------------------------------------------
extern "C" void kernel_launch(void* const* d_in, const int* in_sizes, int n_in,
                              void* d_out, int out_size, void* d_ws, size_t ws_size,
                              hipStream_t stream)
{
    (void)in_sizes; (void)n_in; (void)out_size;
    const float* x_p   = (const float*)d_in[0];
    const float* x_g   = (const float*)d_in[1];
    const float* x_m   = (const float*)d_in[2];
    const int*  src_pg = (const int*)d_in[3];
    const int*  dst_pg = (const int*)d_in[4];
    const int*  src_gp = (const int*)d_in[5];
    const int*  dst_gp = (const int*)d_in[6];
    const int*  src_pm = (const int*)d_in[7];
    const int*  dst_pm = (const int*)d_in[8];
    const int*  src_mp = (const int*)d_in[9];
    const int*  dst_mp = (const int*)d_in[10];
    const float* Win_p = (const float*)d_in[11];
    const float* bin_p = (const float*)d_in[12];
    const float* Win_g = (const float*)d_in[13];
    const float* bin_g = (const float*)d_in[14];
    const float* Win_m = (const float*)d_in[15];
    const float* bin_m = (const float*)d_in[16];
    const float* kw    = (const float*)d_in[17];
    const float* qw    = (const float*)d_in[18];
    const float* vw    = (const float*)d_in[19];
    const float* aw    = (const float*)d_in[20];
    const float* kb    = (const float*)d_in[21];
    const float* qb    = (const float*)d_in[22];
    const float* vb    = (const float*)d_in[23];
    const float* ab    = (const float*)d_in[24];
    const float* skip  = (const float*)d_in[25];
    const float* a_rel = (const float*)d_in[26];
    const float* m_rel = (const float*)d_in[27];
    const float* p_rel = (const float*)d_in[28];
    const float* ca_qw = (const float*)d_in[29];
    const float* ca_kw = (const float*)d_in[30];
    const float* ca_vw = (const float*)d_in[31];
    const float* ca_ow = (const float*)d_in[32];
    const float* ca_qb = (const float*)d_in[33];
    const float* ca_kb = (const float*)d_in[34];
    const float* ca_vb = (const float*)d_in[35];
    const float* ca_ob = (const float*)d_in[36];
    const float* ln_g  = (const float*)d_in[37];
    const float* ln_b  = (const float*)d_in[38];
    const float* outw  = (const float*)d_in[39];
    const float* outb  = (const float*)d_in[40];
    float* dout = (float*)d_out;

    // cross-attn q-row chunk: bigger if the workspace allows the bigger Sbuf
    const int CHV = (ws_size >= (size_t)126 * 1024 * 1024) ? 2048 : 1024;

    // ---- workspace carve-up ----
    float* Wp = (float*)d_ws;
    size_t cursz = 0;
    auto alloc = [&](size_t n) -> float* {
        float* p = Wp + cursz; cursz += (n + 63) & ~(size_t)63; return p;
    };
    float* h0  = alloc((size_t)N0 * HIDF);
    float* h1  = alloc((size_t)N1 * HIDF);
    float* h2  = alloc((size_t)N2 * HIDF);
    float* hg0 = alloc((size_t)N0 * HIDF);
    float* hg1 = alloc((size_t)N1 * HIDF);
    float* hg2 = alloc((size_t)N2 * HIDF);
    float* Q0  = alloc((size_t)N0 * HIDF);
    float* Q1  = alloc((size_t)N1 * HIDF);
    float* Q2  = alloc((size_t)N2 * HIDF);
    float* Kb0 = alloc((size_t)N0 * HIDF);
    float* Kb1 = alloc((size_t)N1 * HIDF);
    float* Kb2 = alloc((size_t)N2 * HIDF);
    float* Vb0 = alloc((size_t)N0 * HIDF);
    float* Vb1 = alloc((size_t)N1 * HIDF);
    float* Vb2 = alloc((size_t)N2 * HIDF);
    const size_t ktvtagg = (size_t)(N0 + N1 + N0 + N2) * 2 * HIDF + (size_t)(N0 + N1 + N2) * HIDF;
    const size_t poolN = max(ktvtagg, (size_t)4 * CHV * 2048);
    float* pool = alloc(poolN);
    float* Kt0 = pool;
    float* Kt1 = Kt0 + (size_t)N0 * HIDF;
    float* Kt2 = Kt1 + (size_t)N1 * HIDF;
    float* Kt3 = Kt2 + (size_t)N0 * HIDF;
    float* Vt0 = Kt3 + (size_t)N2 * HIDF;
    float* Vt1 = Vt0 + (size_t)N0 * HIDF;
    float* Vt2 = Vt1 + (size_t)N1 * HIDF;
    float* Vt3 = Vt2 + (size_t)N0 * HIDF;
    float* agg0 = Vt3 + (size_t)N2 * HIDF;
    float* agg1 = agg0 + (size_t)N0 * HIDF;
    float* agg2 = agg1 + (size_t)N1 * HIDF;
    float* Sbuf = pool;
    float* caq = Kb1; float* cak = Kb0; float* cav = Vb0; float* cao = Vb1;
    int* esrc0  = (int*)alloc(E_GP + E_MP);
    int* eflag0 = (int*)alloc(E_GP + E_MP);
    int* esrc1  = (int*)alloc(E_PG);
    int* eflag1 = (int*)alloc(E_PG);
    int* esrc2  = (int*)alloc(E_PM);
    int* eflag2 = (int*)alloc(E_PM);
    int* off0 = (int*)alloc(N0 + 1); int* cur0 = (int*)alloc(N0);
    int* off1 = (int*)alloc(N1 + 1); int* cur1 = (int*)alloc(N1);
    int* off2 = (int*)alloc(N2 + 1); int* cur2 = (int*)alloc(N2);

    // ---- counting-sort edges by destination (per dst type) ----
    hipMemsetAsync(cur0, 0, N0 * sizeof(int), stream);
    count_kernel<<<(E_GP + 255) / 256, 256, 0, stream>>>(dst_gp, E_GP, cur0);
    count_kernel<<<(E_MP + 255) / 256, 256, 0, stream>>>(dst_mp, E_MP, cur0);
    scan_kernel<<<1, 256, 0, stream>>>(cur0, N0, off0);
    scatter_kernel<<<(E_GP + 255) / 256, 256, 0, stream>>>(src_gp, dst_gp, E_GP, cur0, esrc0, eflag0, 0);
    scatter_kernel<<<(E_MP + 255) / 256, 256, 0, stream>>>(src_mp, dst_mp, E_MP, cur0, esrc0, eflag0, 1);

    hipMemsetAsync(cur1, 0, N1 * sizeof(int), stream);
    count_kernel<<<(E_PG + 255) / 256, 256, 0, stream>>>(dst_pg, E_PG, cur1);
    scan_kernel<<<1, 256, 0, stream>>>(cur1, N1, off1);
    scatter_kernel<<<(E_PG + 255) / 256, 256, 0, stream>>>(src_pg, dst_pg, E_PG, cur1, esrc1, eflag1, 0);

    hipMemsetAsync(cur2, 0, N2 * sizeof(int), stream);
    count_kernel<<<(E_PM + 255) / 256, 256, 0, stream>>>(dst_pm, E_PM, cur2);
    scan_kernel<<<1, 256, 0, stream>>>(cur2, N2, off2);
    scatter_kernel<<<(E_PM + 255) / 256, 256, 0, stream>>>(src_pm, dst_pm, E_PM, cur2, esrc2, eflag2, 0);

    // ---- input projections ----
    launch_gemm(stream, false, x_p, 512, 0, Win_p, HIDF, 0, h0, HIDF, 0, bin_p, N0, HIDF, 512, 1, 1, M_STORE);
    launch_gemm(stream, false, x_g, 768, 0, Win_g, HIDF, 0, h1, HIDF, 0, bin_g, N1, HIDF, 768, 1, 1, M_STORE);
    launch_gemm(stream, false, x_m, 384, 0, Win_m, HIDF, 0, h2, HIDF, 0, bin_m, N2, HIDF, 384, 1, 1, M_STORE);

    float* hptr[3]  = { h0, h1, h2 };
    float* hgptr[3] = { hg0, hg1, hg2 };
    float* Qptr[3]  = { Q0, Q1, Q2 };
    float* Kbp[3]   = { Kb0, Kb1, Kb2 };
    float* Vbp[3]   = { Vb0, Vb1, Vb2 };
    const int Ns[3] = { N0, N1, N2 };

    for (int l = 0; l < 2; l++) {
        // K/Q/V projections, all 3 types x 3 mats in one launch
        {
            GemmDescArr<9> D;
            for (int t = 0; t < 3; t++) {
                const size_t wo = (size_t)(l * 3 + t) * HIDF * HIDF;
                const size_t bo = (size_t)(l * 3 + t) * HIDF;
                D.d[t * 3 + 0] = { hptr[t], qw + wo, Qptr[t], qb + bo, nullptr, nullptr, Ns[t] };
                D.d[t * 3 + 1] = { hptr[t], kw + wo, Kbp[t], kb + bo, nullptr, nullptr, Ns[t] };
                D.d[t * 3 + 2] = { hptr[t], vw + wo, Vbp[t], vb + bo, nullptr, nullptr, Ns[t] };
            }
            gemm_nn_batched<9, M_STORE><<<dim3(4, 64, 9), 256, 0, stream>>>(D, HIDF, HIDF);
        }
        // per-relation node transforms, all 8 in one launch
        {
            const float* ar = a_rel + (size_t)l * 4 * 16384;
            const float* mr = m_rel + (size_t)l * 4 * 16384;
            RelDescArr R;
            R.d[0] = { Kb0, ar + 0 * 16384, Kt0, N0 };
            R.d[1] = { Vb0, mr + 0 * 16384, Vt0, N0 };
            R.d[2] = { Kb1, ar + 1 * 16384, Kt1, N1 };
            R.d[3] = { Vb1, mr + 1 * 16384, Vt1, N1 };
            R.d[4] = { Kb0, ar + 2 * 16384, Kt2, N0 };
            R.d[5] = { Vb0, mr + 2 * 16384, Vt2, N0 };
            R.d[6] = { Kb2, ar + 3 * 16384, Kt3, N2 };
            R.d[7] = { Vb2, mr + 3 * 16384, Vt3, N2 };
            rel_transform_batched<<<dim3(N1 / 16, NHEAD, 8), 256, 0, stream>>>(R);
        }
        // segment-softmax edge attention
        const float* prl = p_rel + (size_t)l * 16;
        edge_attn_kernel<<<N0, 256, 0, stream>>>(Q0, off0, esrc0, eflag0, Kt1, Vt1, Kt3, Vt3, prl, 1, 3, agg0);
        edge_attn_kernel<<<N1, 256, 0, stream>>>(Q1, off1, esrc1, eflag1, Kt0, Vt0, Kt0, Vt0, prl, 0, -1, agg1);
        edge_attn_kernel<<<N2, 256, 0, stream>>>(Q2, off2, esrc2, eflag2, Kt2, Vt2, Kt2, Vt2, prl, 2, -1, agg2);

        // gelu(agg) for all three types in one launch (contiguous in pool)
        gelu4_kernel<<<((N0 + N1 + N2) * HIDF / 4 + 255) / 256, 256, 0, stream>>>(agg0, (N0 + N1 + N2) * HIDF / 4);

        // hg = sigmoid(skip)*(gelu(agg) @ aw + ab) + (1-sigmoid(skip))*h
        {
            GemmDescArr<3> D;
            for (int t = 0; t < 3; t++) {
                const size_t wo = (size_t)(l * 3 + t) * HIDF * HIDF;
                const size_t bo = (size_t)(l * 3 + t) * HIDF;
                float* aggt = (t == 0) ? agg0 : (t == 1 ? agg1 : agg2);
                D.d[t] = { aggt, aw + wo, hgptr[t], ab + bo, skip + l * 3 + t, hptr[t], Ns[t] };
            }
            gemm_nn_batched<3, M_SKIP><<<dim3(4, 64, 3), 256, 0, stream>>>(D, HIDF, HIDF);
        }

        // cross attention: types 1,2 attend to participants (h0)
        for (int t = 1; t <= 2; t++) {
            const int c = t - 1, Nq = Ns[t];
            {
                GemmDescArr<3> D;
                D.d[0] = { hptr[t], ca_qw + (size_t)c * 65536, caq, ca_qb + c * HIDF, nullptr, nullptr, Nq };
                D.d[1] = { h0,      ca_kw + (size_t)c * 65536, cak, ca_kb + c * HIDF, nullptr, nullptr, N0 };
                D.d[2] = { h0,      ca_vw + (size_t)c * 65536, cav, ca_vb + c * HIDF, nullptr, nullptr, N0 };
                gemm_nn_batched<3, M_STORE><<<dim3(4, Nq / 64, 3), 256, 0, stream>>>(D, HIDF, HIDF);
            }
            hipMemsetAsync(cao, 0, (size_t)Nq * HIDF * sizeof(float), stream);
            for (int r0 = 0; r0 < Nq; r0 += CHV) {
                const int rows = min(CHV, Nq - r0);
                launch_gemm(stream, true, caq + (size_t)r0 * HIDF, HIDF, HDIM,
                            cak, HIDF, HDIM, Sbuf, 2048, rows * 2048, nullptr,
                            rows, 2048, HDIM, NHEAD, 1, M_STORE);
                softmax_kernel<<<dim3(rows, NHEAD), 256, 0, stream>>>(Sbuf, rows);
                launch_gemm(stream, false, Sbuf, 2048, rows * 2048, cav, HIDF, HDIM,
                            cao + (size_t)r0 * HIDF, HIDF, HDIM, nullptr,
                            rows, HDIM, 2048, NHEAD, 8, M_ATOMIC);
            }
            launch_gemm(stream, false, cao, HIDF, 0, ca_ow + (size_t)c * 65536, HIDF, 0,
                        hgptr[t], HIDF, 0, ca_ob + c * HIDF, Nq, HIDF, HIDF, 1, 1, M_ADD);
        }

        // h = gelu(LN(h + hg))
        for (int t = 0; t < 3; t++)
            ln_gelu_kernel<<<Ns[t], 256, 0, stream>>>(hptr[t], hgptr[t], ln_g + t * HIDF, ln_b + t * HIDF);
    }

    // ---- output projections (batched, N=128) ----
    {
        GemmDescArr<3> D;
        D.d[0] = { h0, outw + 0,     dout,                            outb,       nullptr, nullptr, N0 };
        D.d[1] = { h1, outw + 32768, dout + (size_t)N0 * OUTF,        outb + 128, nullptr, nullptr, N1 };
        D.d[2] = { h2, outw + 65536, dout + (size_t)(N0 + N1) * OUTF, outb + 256, nullptr, nullptr, N2 };
        gemm_nn_batched<3, M_STORE><<<dim3(2, 64, 3), 256, 0, stream>>>(D, OUTF, HIDF);
    }
}

// Round 3
// 1884.328 us; speedup vs baseline: 1.6594x; 1.1694x over previous
//
#include <hip/hip_runtime.h>
#include <math.h>
#include <stdint.h>
#include <stddef.h>

typedef unsigned short ushort_t;
typedef short  bf16x8 __attribute__((ext_vector_type(8)));
typedef float  f32x4  __attribute__((ext_vector_type(4)));

// ---------------------------------------------------------------------------
static constexpr int NHEAD = 4;
static constexpr int HDIM  = 64;
static constexpr int HIDF  = 256;   // NHEAD*HDIM
static constexpr int OUTF  = 128;
static constexpr int N0 = 2048, N1 = 4096, N2 = 3072;   // participant, gene, metabolite
static constexpr int E_PG = 250000, E_GP = 250000, E_PM = 200000, E_MP = 200000;
static constexpr float ATT_SCALE = 0.125f;              // 1/sqrt(64)

enum { M_STORE = 0, M_ADD = 1, M_SKIP = 2 };

__device__ __forceinline__ float gelu_exact(float x) {
    return 0.5f * x * (1.0f + erff(x * 0.7071067811865476f));
}
__device__ __forceinline__ ushort_t f2bf(float f) {       // RNE fp32->bf16
    unsigned x = __float_as_uint(f);
    return (ushort_t)((x + 0x7fffu + ((x >> 16) & 1u)) >> 16);
}
__device__ __forceinline__ float bflo(unsigned u) { return __uint_as_float(u << 16); }
__device__ __forceinline__ float bfhi(unsigned u) { return __uint_as_float(u & 0xffff0000u); }

// ---------------------------------------------------------------------------
// Simple fp32 NN GEMM: C[M,N] = A[M,K] @ B[K,N] + bias (mode STORE/ADD).
__global__ __launch_bounds__(256) void gemm_simple(
    const float* __restrict__ A, int lda, const float* __restrict__ B,
    float* __restrict__ C, const float* __restrict__ bias,
    int M, int N, int K, int mode)
{
    __shared__ float As[16][64];
    __shared__ float Bs[16][64];
    const int tid = threadIdx.x;
    const int tx = tid & 15, ty = tid >> 4;
    const int bm = blockIdx.y << 6, bn = blockIdx.x << 6;
    const int alr = tid >> 2, alc = (tid & 3) << 2;
    const int blr = tid >> 4, blc = (tid & 15) << 2;

    float acc[4][4] = {};
    for (int k0 = 0; k0 < K; k0 += 16) {
        float4 av = *(const float4*)(A + (size_t)(bm + alr) * lda + k0 + alc);
        As[alc + 0][alr] = av.x; As[alc + 1][alr] = av.y;
        As[alc + 2][alr] = av.z; As[alc + 3][alr] = av.w;
        float4 bv = *(const float4*)(B + (size_t)(k0 + blr) * N + bn + blc);
        *(float4*)&Bs[blr][blc] = bv;
        __syncthreads();
#pragma unroll
        for (int kk = 0; kk < 16; kk++) {
            const float4 a4 = *(const float4*)&As[kk][ty << 2];
            const float4 b4 = *(const float4*)&Bs[kk][tx << 2];
            acc[0][0] = fmaf(a4.x, b4.x, acc[0][0]); acc[0][1] = fmaf(a4.x, b4.y, acc[0][1]);
            acc[0][2] = fmaf(a4.x, b4.z, acc[0][2]); acc[0][3] = fmaf(a4.x, b4.w, acc[0][3]);
            acc[1][0] = fmaf(a4.y, b4.x, acc[1][0]); acc[1][1] = fmaf(a4.y, b4.y, acc[1][1]);
            acc[1][2] = fmaf(a4.y, b4.z, acc[1][2]); acc[1][3] = fmaf(a4.y, b4.w, acc[1][3]);
            acc[2][0] = fmaf(a4.z, b4.x, acc[2][0]); acc[2][1] = fmaf(a4.z, b4.y, acc[2][1]);
            acc[2][2] = fmaf(a4.z, b4.z, acc[2][2]); acc[2][3] = fmaf(a4.z, b4.w, acc[2][3]);
            acc[3][0] = fmaf(a4.w, b4.x, acc[3][0]); acc[3][1] = fmaf(a4.w, b4.y, acc[3][1]);
            acc[3][2] = fmaf(a4.w, b4.z, acc[3][2]); acc[3][3] = fmaf(a4.w, b4.w, acc[3][3]);
        }
        __syncthreads();
    }
#pragma unroll
    for (int i = 0; i < 4; i++) {
        const int mrow = bm + (ty << 2) + i;
        float* crow = C + (size_t)mrow * N + bn + (tx << 2);
#pragma unroll
        for (int j = 0; j < 4; j++) {
            float v = acc[i][j] + bias[bn + (tx << 2) + j];
            if (mode == M_ADD) crow[j] += v; else crow[j] = v;
        }
    }
}

// ---------------------------------------------------------------------------
// Descriptor-batched NN GEMM (A[M,256/K] @ B[K,N]); B16 => C is bf16.
struct GemmDesc {
    const float* A; const float* B; float* C;
    const float* bias; const float* skipv; const float* H;
    int M;
};
template <int NZ> struct GemmDescArr { GemmDesc d[NZ]; };

template <int NZ, int MODE, bool B16>
__global__ __launch_bounds__(256) void gemm_nn_batched(GemmDescArr<NZ> P, int N, int K)
{
    const GemmDesc g = P.d[blockIdx.z];
    const int bm = blockIdx.y << 6;
    if (bm >= g.M) return;
    const int bn = blockIdx.x << 6;

    __shared__ float As[16][64];
    __shared__ float Bs[16][64];
    const int tid = threadIdx.x;
    const int tx = tid & 15, ty = tid >> 4;
    const int alr = tid >> 2, alc = (tid & 3) << 2;
    const int blr = tid >> 4, blc = (tid & 15) << 2;

    float acc[4][4] = {};
    for (int k0 = 0; k0 < K; k0 += 16) {
        float4 av = *(const float4*)(g.A + (size_t)(bm + alr) * K + k0 + alc);
        As[alc + 0][alr] = av.x; As[alc + 1][alr] = av.y;
        As[alc + 2][alr] = av.z; As[alc + 3][alr] = av.w;
        float4 bv = *(const float4*)(g.B + (size_t)(k0 + blr) * N + bn + blc);
        *(float4*)&Bs[blr][blc] = bv;
        __syncthreads();
#pragma unroll
        for (int kk = 0; kk < 16; kk++) {
            const float4 a4 = *(const float4*)&As[kk][ty << 2];
            const float4 b4 = *(const float4*)&Bs[kk][tx << 2];
            acc[0][0] = fmaf(a4.x, b4.x, acc[0][0]); acc[0][1] = fmaf(a4.x, b4.y, acc[0][1]);
            acc[0][2] = fmaf(a4.x, b4.z, acc[0][2]); acc[0][3] = fmaf(a4.x, b4.w, acc[0][3]);
            acc[1][0] = fmaf(a4.y, b4.x, acc[1][0]); acc[1][1] = fmaf(a4.y, b4.y, acc[1][1]);
            acc[1][2] = fmaf(a4.y, b4.z, acc[1][2]); acc[1][3] = fmaf(a4.y, b4.w, acc[1][3]);
            acc[2][0] = fmaf(a4.z, b4.x, acc[2][0]); acc[2][1] = fmaf(a4.z, b4.y, acc[2][1]);
            acc[2][2] = fmaf(a4.z, b4.z, acc[2][2]); acc[2][3] = fmaf(a4.z, b4.w, acc[2][3]);
            acc[3][0] = fmaf(a4.w, b4.x, acc[3][0]); acc[3][1] = fmaf(a4.w, b4.y, acc[3][1]);
            acc[3][2] = fmaf(a4.w, b4.z, acc[3][2]); acc[3][3] = fmaf(a4.w, b4.w, acc[3][3]);
        }
        __syncthreads();
    }

    float gblend = 0.f, hblend = 0.f;
    if (MODE == M_SKIP) {
        const float sv = g.skipv[0];
        gblend = 1.f / (1.f + expf(-sv));
        hblend = 1.f - gblend;
    }
#pragma unroll
    for (int i = 0; i < 4; i++) {
        const int mrow = bm + (ty << 2) + i;
#pragma unroll
        for (int j = 0; j < 4; j++) {
            const int col = bn + (tx << 2) + j;
            float v = acc[i][j] + g.bias[col];
            if (B16) {
                ((ushort_t*)g.C)[(size_t)mrow * N + col] = f2bf(v);
            } else if (MODE == M_SKIP) {
                g.C[(size_t)mrow * N + col] =
                    gblend * v + hblend * g.H[(size_t)mrow * N + col];
            } else {
                g.C[(size_t)mrow * N + col] = v;
            }
        }
    }
}

// ---------------------------------------------------------------------------
// Per-node, per-head 64x64 transforms (batched descriptors, optional 2-term):
//  trw=0: Y[n,h,f] = sum_d X1[n,h,d] W1[h,d,f]  (+ X2 W2)
//  trw=1: Y[n,h,d] = sum_f X1[n,h,f] W1[h,d,f]           (Q' trick)
struct RelDesc2 { const float* X1; const float* W1; const float* X2; const float* W2;
                  float* Y; int rows; int trw; };
template <int ND> struct RelDesc2Arr { RelDesc2 d[ND]; };

template <int ND>
__global__ __launch_bounds__(256) void rel2_kernel(RelDesc2Arr<ND> P)
{
    const RelDesc2 g = P.d[blockIdx.z];
    const int n0 = blockIdx.x << 4;
    if (n0 >= g.rows) return;
    __shared__ float Ws1[64][65];
    __shared__ float Ws2[64][65];
    __shared__ float Xs1[16][64];
    __shared__ float Xs2[16][64];
    const int h = blockIdx.y, tid = threadIdx.x;
    const bool two = (g.X2 != nullptr);
    const float* W1h = g.W1 + (h << 12);
    for (int i = tid; i < 4096; i += 256) {
        const float wv = W1h[i];
        if (g.trw) Ws1[i & 63][i >> 6] = wv; else Ws1[i >> 6][i & 63] = wv;
    }
    for (int i = tid; i < 1024; i += 256)
        Xs1[i >> 6][i & 63] = g.X1[(size_t)(n0 + (i >> 6)) * HIDF + (h << 6) + (i & 63)];
    if (two) {
        const float* W2h = g.W2 + (h << 12);
        for (int i = tid; i < 4096; i += 256) {
            const float wv = W2h[i];
            if (g.trw) Ws2[i & 63][i >> 6] = wv; else Ws2[i >> 6][i & 63] = wv;
        }
        for (int i = tid; i < 1024; i += 256)
            Xs2[i >> 6][i & 63] = g.X2[(size_t)(n0 + (i >> 6)) * HIDF + (h << 6) + (i & 63)];
    }
    __syncthreads();
    const int r = tid >> 4, f0 = (tid & 15) << 2;
    float a0 = 0, a1 = 0, a2 = 0, a3 = 0;
#pragma unroll 8
    for (int d = 0; d < 64; d++) {
        const float x1 = Xs1[r][d];
        a0 = fmaf(x1, Ws1[d][f0 + 0], a0);
        a1 = fmaf(x1, Ws1[d][f0 + 1], a1);
        a2 = fmaf(x1, Ws1[d][f0 + 2], a2);
        a3 = fmaf(x1, Ws1[d][f0 + 3], a3);
    }
    if (two) {
#pragma unroll 8
        for (int d = 0; d < 64; d++) {
            const float x2 = Xs2[r][d];
            a0 = fmaf(x2, Ws2[d][f0 + 0], a0);
            a1 = fmaf(x2, Ws2[d][f0 + 1], a1);
            a2 = fmaf(x2, Ws2[d][f0 + 2], a2);
            a3 = fmaf(x2, Ws2[d][f0 + 3], a3);
        }
    }
    const size_t yb = (size_t)(n0 + r) * HIDF + (h << 6) + f0;
    g.Y[yb] = a0; g.Y[yb + 1] = a1; g.Y[yb + 2] = a2; g.Y[yb + 3] = a3;
}

// ---------------------------------------------------------------------------
// Counting sort by destination
__global__ void count_kernel(const int* __restrict__ dst, int E, int* __restrict__ cnt)
{
    int i = blockIdx.x * 256 + threadIdx.x;
    if (i < E) atomicAdd(&cnt[dst[i]], 1);
}

__global__ __launch_bounds__(256) void scan_kernel(int* __restrict__ cntcur, int N, int* __restrict__ off)
{
    __shared__ int sums[256];
    const int tid = threadIdx.x;
    const int base = tid * 16;
    int vals[16];
    int s = 0;
#pragma unroll
    for (int j = 0; j < 16; j++) {
        int idx = base + j;
        int c = (idx < N) ? cntcur[idx] : 0;
        vals[j] = s; s += c;
    }
    sums[tid] = s;
    __syncthreads();
    for (int d = 1; d < 256; d <<= 1) {
        int v = (tid >= d) ? sums[tid - d] : 0;
        __syncthreads();
        sums[tid] += v;
        __syncthreads();
    }
    int prefix = (tid > 0) ? sums[tid - 1] : 0;
#pragma unroll
    for (int j = 0; j < 16; j++) {
        int idx = base + j;
        if (idx < N) { int v = prefix + vals[j]; off[idx] = v; cntcur[idx] = v; }
    }
    if (tid == 255) off[N] = sums[255];
}

__global__ void scatter_kernel(const int* __restrict__ src, const int* __restrict__ dst, int E,
                               int* __restrict__ cur, int* __restrict__ esrc)
{
    int i = blockIdx.x * 256 + threadIdx.x;
    if (i < E) esrc[atomicAdd(&cur[dst[i]], 1)] = src[i];
}

// ---------------------------------------------------------------------------
// HGT edge attention, Q'-form: score = (Q' . K[src]) * prel * SCALE,
// accumulates raw-V partial sums per relation (m_rel applied later).
// Barrier-free: wave h = head h, bf16 K/V gather tables.
__device__ __forceinline__ void edge_rel_process(
    const float* qsrow, const int* __restrict__ esrc, int i0, int i1,
    const ushort_t* __restrict__ Kt, const ushort_t* __restrict__ Vt,
    float pscale, int lane, int h,
    float& m, float& lsum, float& accCur, float& accOth)
{
    for (int c = i0; c < i1; c += 64) {
        const int e = c + lane;
        float a = -INFINITY;
        int sidx = 0;
        if (e < i1) {
            sidx = esrc[e];
            const uint4* kr = (const uint4*)(Kt + ((size_t)sidx << 8) + (h << 6));
            float dot = 0.f;
#pragma unroll
            for (int u = 0; u < 8; u++) {
                const uint4 kv = kr[u];
                const float4 q0 = *(const float4*)(qsrow + (u << 3));
                const float4 q1 = *(const float4*)(qsrow + (u << 3) + 4);
                dot = fmaf(bflo(kv.x), q0.x, dot); dot = fmaf(bfhi(kv.x), q0.y, dot);
                dot = fmaf(bflo(kv.y), q0.z, dot); dot = fmaf(bfhi(kv.y), q0.w, dot);
                dot = fmaf(bflo(kv.z), q1.x, dot); dot = fmaf(bfhi(kv.z), q1.y, dot);
                dot = fmaf(bflo(kv.w), q1.z, dot); dot = fmaf(bfhi(kv.w), q1.w, dot);
            }
            a = dot * pscale;
        }
        float cm = a;
#pragma unroll
        for (int o = 32; o; o >>= 1) cm = fmaxf(cm, __shfl_xor(cm, o));
        const float mn = fmaxf(m, cm);
        const float scale = (m == -INFINITY) ? 0.f : expf(m - mn);
        const float w = (e < i1) ? expf(a - mn) : 0.f;
        float wsum = w;
#pragma unroll
        for (int o = 32; o; o >>= 1) wsum += __shfl_xor(wsum, o);
        lsum = lsum * scale + wsum;
        m = mn;
        accCur *= scale;
        accOth *= scale;
        const int nv = (i1 - c < 64) ? (i1 - c) : 64;
#pragma unroll 4
        for (int e2 = 0; e2 < nv; e2++) {
            const float w2 = __shfl(w, e2);
            const int s2 = __shfl(sidx, e2);
            const float v = bflo((unsigned)Vt[((size_t)s2 << 8) + (h << 6) + lane]);
            accCur = fmaf(w2, v, accCur);
        }
    }
}

__global__ __launch_bounds__(256) void edge_attn3(
    const float* __restrict__ QpA, const float* __restrict__ QpB,
    const int* __restrict__ offA, const int* __restrict__ esA,
    const int* __restrict__ offB, const int* __restrict__ esB,
    const ushort_t* __restrict__ KA, const ushort_t* __restrict__ VA,
    const ushort_t* __restrict__ KB, const ushort_t* __restrict__ VB,
    const float* __restrict__ prel, int ra, int rb,
    float* __restrict__ outA, float* __restrict__ outB)
{
    __shared__ float Qs[2][NHEAD][HDIM];
    const int dstn = blockIdx.x;
    const int tid = threadIdx.x, lane = tid & 63, h = tid >> 6;
    Qs[0][h][lane] = QpA[(size_t)dstn * HIDF + (h << 6) + lane];
    if (rb >= 0) Qs[1][h][lane] = QpB[(size_t)dstn * HIDF + (h << 6) + lane];
    // same-wave LDS write->read; no block barrier needed (waves independent)
    float m = -INFINITY, lsum = 0.f, accA = 0.f, accB = 0.f;
    const float psA = prel[ra * NHEAD + h] * ATT_SCALE;
    edge_rel_process(&Qs[0][h][0], esA, offA[dstn], offA[dstn + 1], KA, VA, psA,
                     lane, h, m, lsum, accA, accB);
    if (rb >= 0) {
        const float psB = prel[rb * NHEAD + h] * ATT_SCALE;
        edge_rel_process(&Qs[1][h][0], esB, offB[dstn], offB[dstn + 1], KB, VB, psB,
                         lane, h, m, lsum, accB, accA);
    }
    const float inv = (lsum > 0.f) ? 1.f / lsum : 0.f;
    outA[(size_t)dstn * HIDF + (h << 6) + lane] = accA * inv;
    if (rb >= 0) outB[(size_t)dstn * HIDF + (h << 6) + lane] = accB * inv;
}

// ---------------------------------------------------------------------------
__global__ void gelu4_kernel(float* __restrict__ x, int n4)
{
    int i = blockIdx.x * 256 + threadIdx.x;
    if (i < n4) {
        float4 v = ((float4*)x)[i];
        v.x = gelu_exact(v.x); v.y = gelu_exact(v.y);
        v.z = gelu_exact(v.z); v.w = gelu_exact(v.w);
        ((float4*)x)[i] = v;
    }
}

// [N][256] fp32 -> [4][N][64] bf16 (optionally scaled)
__global__ void cast_split_kernel(const float* __restrict__ in, ushort_t* __restrict__ out,
                                  int Nrows, float scale)
{
    int i = blockIdx.x * 256 + threadIdx.x;
    if (i < Nrows * HIDF) {
        const int n = i >> 8, c = i & 255, hh = c >> 6, d = c & 63;
        out[((size_t)hh * Nrows + n) * 64 + d] = f2bf(in[i] * scale);
    }
}

// [N][256] fp32 -> [4][64][N] bf16 (per-head transpose)
__global__ __launch_bounds__(256) void transposeV_kernel(
    const float* __restrict__ in, ushort_t* __restrict__ out, int Nrows)
{
    __shared__ float Ls[64][65];
    const int h = blockIdx.y, n0 = blockIdx.x << 6, tid = threadIdx.x;
    const int c = tid & 63, rq = tid >> 6;
    for (int rr = rq; rr < 64; rr += 4)
        Ls[rr][c] = in[(size_t)(n0 + rr) * HIDF + (h << 6) + c];
    __syncthreads();
    for (int dd = rq; dd < 64; dd += 4)
        out[((size_t)(h * 64 + dd)) * Nrows + n0 + c] = f2bf(Ls[c][dd]);
}

// ---------------------------------------------------------------------------
// Flash cross-attention: O[q, h*64+d] = softmax(Q K^T) V, bf16 MFMA.
// Grid (Nq/64, 4 heads); 4 waves, each owns 16 q-rows; K/V read from L2.
__global__ __launch_bounds__(256) void flash_ca(
    const ushort_t* __restrict__ qh, const ushort_t* __restrict__ kh,
    const ushort_t* __restrict__ vT, float* __restrict__ O, int Nq, int Nk)
{
    __shared__ ushort_t Pl[4][16][72];
    const int head = blockIdx.y;
    const int q0 = blockIdx.x << 6;
    const int tid = threadIdx.x, wave = tid >> 6, lane = tid & 63;
    const int l15 = lane & 15, lg = lane >> 4;

    const ushort_t* qbase = qh + ((size_t)head * Nq + q0 + (wave << 4) + l15) * 64 + (lg << 3);
    const bf16x8 qa0 = *(const bf16x8*)qbase;
    const bf16x8 qa1 = *(const bf16x8*)(qbase + 32);
    const ushort_t* kbase = kh + (size_t)head * Nk * 64;
    const ushort_t* vbase = vT + (size_t)head * 64 * Nk;

    f32x4 o[4] = {{0,0,0,0},{0,0,0,0},{0,0,0,0},{0,0,0,0}};
    float m[4]    = {-INFINITY, -INFINITY, -INFINITY, -INFINITY};
    float lsum[4] = {0.f, 0.f, 0.f, 0.f};

    const int nkt = Nk >> 6;
    for (int kt = 0; kt < nkt; kt++) {
        const int k0 = kt << 6;
        f32x4 s[4] = {{0,0,0,0},{0,0,0,0},{0,0,0,0},{0,0,0,0}};
        const ushort_t* krow = kbase + ((size_t)(k0 + l15)) * 64 + (lg << 3);
#pragma unroll
        for (int ct = 0; ct < 4; ct++) {
            const bf16x8 b = *(const bf16x8*)(krow + (ct << 10));
            s[ct] = __builtin_amdgcn_mfma_f32_16x16x32_bf16(qa0, b, s[ct], 0, 0, 0);
        }
#pragma unroll
        for (int ct = 0; ct < 4; ct++) {
            const bf16x8 b = *(const bf16x8*)(krow + (ct << 10) + 32);
            s[ct] = __builtin_amdgcn_mfma_f32_16x16x32_bf16(qa1, b, s[ct], 0, 0, 0);
        }
        // online softmax over this 64-key tile (C layout: col=l15, row=lg*4+r)
        float tm[4], sc[4], ts[4];
#pragma unroll
        for (int r = 0; r < 4; r++)
            tm[r] = fmaxf(fmaxf(s[0][r], s[1][r]), fmaxf(s[2][r], s[3][r]));
#pragma unroll
        for (int off = 1; off <= 8; off <<= 1)
#pragma unroll
            for (int r = 0; r < 4; r++)
                tm[r] = fmaxf(tm[r], __shfl_xor(tm[r], off));
#pragma unroll
        for (int r = 0; r < 4; r++) {
            const float mn = fmaxf(m[r], tm[r]);
            sc[r] = expf(m[r] - mn);
            m[r] = mn;
            ts[r] = 0.f;
        }
#pragma unroll
        for (int ct = 0; ct < 4; ct++)
#pragma unroll
            for (int r = 0; r < 4; r++) {
                const float p = expf(s[ct][r] - m[r]);
                ts[r] += p;
                Pl[wave][(lg << 2) + r][(ct << 4) + l15] = f2bf(p);
            }
#pragma unroll
        for (int off = 1; off <= 8; off <<= 1)
#pragma unroll
            for (int r = 0; r < 4; r++)
                ts[r] += __shfl_xor(ts[r], off);
#pragma unroll
        for (int r = 0; r < 4; r++)
            lsum[r] = lsum[r] * sc[r] + ts[r];
#pragma unroll
        for (int vt = 0; vt < 4; vt++)
#pragma unroll
            for (int r = 0; r < 4; r++)
                o[vt][r] *= sc[r];
        // P fragments (same-wave LDS round-trip; lgkmcnt handled by compiler)
        const bf16x8 pa0 = *(const bf16x8*)&Pl[wave][l15][lg << 3];
        const bf16x8 pa1 = *(const bf16x8*)&Pl[wave][l15][32 + (lg << 3)];
        const ushort_t* vrow = vbase + (size_t)l15 * Nk + k0 + (lg << 3);
#pragma unroll
        for (int vt = 0; vt < 4; vt++) {
            const bf16x8 b = *(const bf16x8*)(vrow + (size_t)(vt << 4) * Nk);
            o[vt] = __builtin_amdgcn_mfma_f32_16x16x32_bf16(pa0, b, o[vt], 0, 0, 0);
        }
#pragma unroll
        for (int vt = 0; vt < 4; vt++) {
            const bf16x8 b = *(const bf16x8*)(vrow + (size_t)(vt << 4) * Nk + 32);
            o[vt] = __builtin_amdgcn_mfma_f32_16x16x32_bf16(pa1, b, o[vt], 0, 0, 0);
        }
    }
    float inv[4];
#pragma unroll
    for (int r = 0; r < 4; r++) inv[r] = 1.f / lsum[r];
#pragma unroll
    for (int vt = 0; vt < 4; vt++)
#pragma unroll
        for (int r = 0; r < 4; r++)
            O[(size_t)(q0 + (wave << 4) + (lg << 2) + r) * HIDF
              + (head << 6) + (vt << 4) + l15] = o[vt][r] * inv[r];
}

// ---------------------------------------------------------------------------
// Fused residual + LayerNorm + exact GELU (in-place update of h).
__global__ __launch_bounds__(256) void ln_gelu_kernel(
    float* __restrict__ h, const float* __restrict__ hg,
    const float* __restrict__ g, const float* __restrict__ b)
{
    __shared__ float t4[4];
    const int row = blockIdx.x, tid = threadIdx.x, lane = tid & 63, w = tid >> 6;
    const size_t idx = (size_t)row * HIDF + tid;
    const float x = h[idx] + hg[idx];
    float v = x;
#pragma unroll
    for (int o = 32; o; o >>= 1) v += __shfl_xor(v, o);
    if (lane == 0) t4[w] = v;
    __syncthreads();
    const float mean = (t4[0] + t4[1] + t4[2] + t4[3]) * (1.f / 256.f);
    __syncthreads();
    const float d = x - mean;
    v = d * d;
#pragma unroll
    for (int o = 32; o; o >>= 1) v += __shfl_xor(v, o);
    if (lane == 0) t4[w] = v;
    __syncthreads();
    const float var = (t4[0] + t4[1] + t4[2] + t4[3]) * (1.f / 256.f);
    const float y = d * rsqrtf(var + 1e-5f) * g[tid] + b[tid];
    h[idx] = gelu_exact(y);
}

// ---------------------------------------------------------------------------
extern "C" void kernel_launch(void* const* d_in, const int* in_sizes, int n_in,
                              void* d_out, int out_size, void* d_ws, size_t ws_size,
                              hipStream_t stream)
{
    (void)in_sizes; (void)n_in; (void)out_size; (void)ws_size;
    const float* x_p   = (const float*)d_in[0];
    const float* x_g   = (const float*)d_in[1];
    const float* x_m   = (const float*)d_in[2];
    const int*  src_pg = (const int*)d_in[3];
    const int*  dst_pg = (const int*)d_in[4];
    const int*  src_gp = (const int*)d_in[5];
    const int*  dst_gp = (const int*)d_in[6];
    const int*  src_pm = (const int*)d_in[7];
    const int*  dst_pm = (const int*)d_in[8];
    const int*  src_mp = (const int*)d_in[9];
    const int*  dst_mp = (const int*)d_in[10];
    const float* Win_p = (const float*)d_in[11];
    const float* bin_p = (const float*)d_in[12];
    const float* Win_g = (const float*)d_in[13];
    const float* bin_g = (const float*)d_in[14];
    const float* Win_m = (const float*)d_in[15];
    const float* bin_m = (const float*)d_in[16];
    const float* kw    = (const float*)d_in[17];
    const float* qw    = (const float*)d_in[18];
    const float* vw    = (const float*)d_in[19];
    const float* aw    = (const float*)d_in[20];
    const float* kb    = (const float*)d_in[21];
    const float* qb    = (const float*)d_in[22];
    const float* vb    = (const float*)d_in[23];
    const float* ab    = (const float*)d_in[24];
    const float* skip  = (const float*)d_in[25];
    const float* a_rel = (const float*)d_in[26];
    const float* m_rel = (const float*)d_in[27];
    const float* p_rel = (const float*)d_in[28];
    const float* ca_qw = (const float*)d_in[29];
    const float* ca_kw = (const float*)d_in[30];
    const float* ca_vw = (const float*)d_in[31];
    const float* ca_ow = (const float*)d_in[32];
    const float* ca_qb = (const float*)d_in[33];
    const float* ca_kb = (const float*)d_in[34];
    const float* ca_vb = (const float*)d_in[35];
    const float* ca_ob = (const float*)d_in[36];
    const float* ln_g  = (const float*)d_in[37];
    const float* ln_b  = (const float*)d_in[38];
    const float* outw  = (const float*)d_in[39];
    const float* outb  = (const float*)d_in[40];
    float* dout = (float*)d_out;

    // ---- workspace carve-up ----
    float* Wp = (float*)d_ws;
    size_t cursz = 0;
    auto alloc = [&](size_t n) -> float* {
        float* p = Wp + cursz; cursz += (n + 63) & ~(size_t)63; return p;
    };
    const size_t NT = N0 + N1 + N2;               // 9216
    float* h0  = alloc((size_t)N0 * HIDF);
    float* h1  = alloc((size_t)N1 * HIDF);
    float* h2  = alloc((size_t)N2 * HIDF);
    float* hg0 = alloc((size_t)N0 * HIDF);
    float* hg1 = alloc((size_t)N1 * HIDF);
    float* hg2 = alloc((size_t)N2 * HIDF);
    float* Q0  = alloc((size_t)N0 * HIDF);
    float* Q1  = alloc((size_t)N1 * HIDF);
    float* Q2  = alloc((size_t)N2 * HIDF);
    ushort_t* K16 = (ushort_t*)alloc(NT * HIDF / 2);
    ushort_t* V16 = (ushort_t*)alloc(NT * HIDF / 2);
    ushort_t* K16_0 = K16, *K16_1 = K16 + (size_t)N0 * HIDF, *K16_2 = K16 + (size_t)(N0 + N1) * HIDF;
    ushort_t* V16_0 = V16, *V16_1 = V16 + (size_t)N0 * HIDF, *V16_2 = V16 + (size_t)(N0 + N1) * HIDF;
    float* QpPool  = alloc((size_t)(N1 + N0 + N2 + N0) * HIDF);   // 11264 rows
    float* Qp0 = QpPool;
    float* Qp1 = Qp0 + (size_t)N1 * HIDF;
    float* Qp2 = Qp1 + (size_t)N0 * HIDF;
    float* Qp3 = Qp2 + (size_t)N2 * HIDF;
    float* PartPool = alloc((size_t)(N0 + N0 + N1 + N2) * HIDF);  // 11264 rows
    float* pA0 = PartPool;
    float* pB0 = pA0 + (size_t)N0 * HIDF;
    float* p1  = pB0 + (size_t)N0 * HIDF;
    float* p2  = p1 + (size_t)N1 * HIDF;
    float* agg0 = alloc(NT * HIDF);
    float* agg1 = agg0 + (size_t)N0 * HIDF;
    float* agg2 = agg1 + (size_t)N1 * HIDF;
    // CA fp32 buffers alias Qp+Part pools (dead during cross-attention)
    float* caq = QpPool;
    float* cak = caq + (size_t)N1 * HIDF;
    float* cav = cak + (size_t)N0 * HIDF;
    float* cao = cav + (size_t)N0 * HIDF;
    // CA bf16 tables alias agg (dead during cross-attention)
    ushort_t* qh16 = (ushort_t*)agg0;
    ushort_t* kh16 = qh16 + (size_t)NHEAD * N1 * HDIM;
    ushort_t* vT16 = kh16 + (size_t)NHEAD * N0 * HDIM;
    int* es_gp = (int*)alloc(E_GP);
    int* es_mp = (int*)alloc(E_MP);
    int* es_pg = (int*)alloc(E_PG);
    int* es_pm = (int*)alloc(E_PM);
    int* off_gp = (int*)alloc(N0 + 1); int* cur_gp = (int*)alloc(N0);
    int* off_mp = (int*)alloc(N0 + 1); int* cur_mp = (int*)alloc(N0);
    int* off_pg = (int*)alloc(N1 + 1); int* cur_pg = (int*)alloc(N1);
    int* off_pm = (int*)alloc(N2 + 1); int* cur_pm = (int*)alloc(N2);

    // ---- counting-sort edges by destination (4 independent CSRs) ----
    hipMemsetAsync(cur_gp, 0, N0 * sizeof(int), stream);
    count_kernel<<<(E_GP + 255) / 256, 256, 0, stream>>>(dst_gp, E_GP, cur_gp);
    scan_kernel<<<1, 256, 0, stream>>>(cur_gp, N0, off_gp);
    scatter_kernel<<<(E_GP + 255) / 256, 256, 0, stream>>>(src_gp, dst_gp, E_GP, cur_gp, es_gp);

    hipMemsetAsync(cur_mp, 0, N0 * sizeof(int), stream);
    count_kernel<<<(E_MP + 255) / 256, 256, 0, stream>>>(dst_mp, E_MP, cur_mp);
    scan_kernel<<<1, 256, 0, stream>>>(cur_mp, N0, off_mp);
    scatter_kernel<<<(E_MP + 255) / 256, 256, 0, stream>>>(src_mp, dst_mp, E_MP, cur_mp, es_mp);

    hipMemsetAsync(cur_pg, 0, N1 * sizeof(int), stream);
    count_kernel<<<(E_PG + 255) / 256, 256, 0, stream>>>(dst_pg, E_PG, cur_pg);
    scan_kernel<<<1, 256, 0, stream>>>(cur_pg, N1, off_pg);
    scatter_kernel<<<(E_PG + 255) / 256, 256, 0, stream>>>(src_pg, dst_pg, E_PG, cur_pg, es_pg);

    hipMemsetAsync(cur_pm, 0, N2 * sizeof(int), stream);
    count_kernel<<<(E_PM + 255) / 256, 256, 0, stream>>>(dst_pm, E_PM, cur_pm);
    scan_kernel<<<1, 256, 0, stream>>>(cur_pm, N2, off_pm);
    scatter_kernel<<<(E_PM + 255) / 256, 256, 0, stream>>>(src_pm, dst_pm, E_PM, cur_pm, es_pm);

    // ---- input projections ----
    gemm_simple<<<dim3(HIDF / 64, N0 / 64), 256, 0, stream>>>(x_p, 512, Win_p, h0, bin_p, N0, HIDF, 512, M_STORE);
    gemm_simple<<<dim3(HIDF / 64, N1 / 64), 256, 0, stream>>>(x_g, 768, Win_g, h1, bin_g, N1, HIDF, 768, M_STORE);
    gemm_simple<<<dim3(HIDF / 64, N2 / 64), 256, 0, stream>>>(x_m, 384, Win_m, h2, bin_m, N2, HIDF, 384, M_STORE);

    float* hptr[3]  = { h0, h1, h2 };
    float* hgptr[3] = { hg0, hg1, hg2 };
    float* Qptr[3]  = { Q0, Q1, Q2 };
    ushort_t* Kp[3] = { K16_0, K16_1, K16_2 };
    ushort_t* Vp[3] = { V16_0, V16_1, V16_2 };
    const int Ns[3] = { N0, N1, N2 };

    for (int l = 0; l < 2; l++) {
        // Q projections (fp32) — feeds Q' transform
        {
            GemmDescArr<3> D;
            for (int t = 0; t < 3; t++) {
                const size_t wo = (size_t)(l * 3 + t) * HIDF * HIDF;
                const size_t bo = (size_t)(l * 3 + t) * HIDF;
                D.d[t] = { hptr[t], qw + wo, Qptr[t], qb + bo, nullptr, nullptr, Ns[t] };
            }
            gemm_nn_batched<3, M_STORE, false><<<dim3(4, 64, 3), 256, 0, stream>>>(D, HIDF, HIDF);
        }
        // K/V projections written directly as bf16 gather tables
        {
            GemmDescArr<6> D;
            for (int t = 0; t < 3; t++) {
                const size_t wo = (size_t)(l * 3 + t) * HIDF * HIDF;
                const size_t bo = (size_t)(l * 3 + t) * HIDF;
                D.d[t]     = { hptr[t], kw + wo, (float*)Kp[t], kb + bo, nullptr, nullptr, Ns[t] };
                D.d[3 + t] = { hptr[t], vw + wo, (float*)Vp[t], vb + bo, nullptr, nullptr, Ns[t] };
            }
            gemm_nn_batched<6, M_STORE, true><<<dim3(4, 64, 6), 256, 0, stream>>>(D, HIDF, HIDF);
        }
        // Q' = a_rel[h] @ Q per dst node (trw=1), 4 relations in one launch
        {
            const float* ar = a_rel + (size_t)l * 4 * 16384;
            RelDesc2Arr<4> R;
            R.d[0] = { Q1, ar + 0 * 16384, nullptr, nullptr, Qp0, N1, 1 };
            R.d[1] = { Q0, ar + 1 * 16384, nullptr, nullptr, Qp1, N0, 1 };
            R.d[2] = { Q2, ar + 2 * 16384, nullptr, nullptr, Qp2, N2, 1 };
            R.d[3] = { Q0, ar + 3 * 16384, nullptr, nullptr, Qp3, N0, 1 };
            rel2_kernel<4><<<dim3(N1 / 16, NHEAD, 4), 256, 0, stream>>>(R);
        }
        // segment-softmax edge attention (raw-V partial sums per relation)
        const float* prl = p_rel + (size_t)l * 16;
        edge_attn3<<<N0, 256, 0, stream>>>(Qp1, Qp3, off_gp, es_gp, off_mp, es_mp,
                                           K16_1, V16_1, K16_2, V16_2, prl, 1, 3, pA0, pB0);
        edge_attn3<<<N1, 256, 0, stream>>>(Qp0, nullptr, off_pg, es_pg, nullptr, nullptr,
                                           K16_0, V16_0, nullptr, nullptr, prl, 0, -1, p1, nullptr);
        edge_attn3<<<N2, 256, 0, stream>>>(Qp2, nullptr, off_pm, es_pm, nullptr, nullptr,
                                           K16_0, V16_0, nullptr, nullptr, prl, 2, -1, p2, nullptr);
        // agg = sum_r partial_r @ m_rel[r]
        {
            const float* mr = m_rel + (size_t)l * 4 * 16384;
            RelDesc2Arr<3> R;
            R.d[0] = { pA0, mr + 1 * 16384, pB0, mr + 3 * 16384, agg0, N0, 0 };
            R.d[1] = { p1,  mr + 0 * 16384, nullptr, nullptr,    agg1, N1, 0 };
            R.d[2] = { p2,  mr + 2 * 16384, nullptr, nullptr,    agg2, N2, 0 };
            rel2_kernel<3><<<dim3(N1 / 16, NHEAD, 3), 256, 0, stream>>>(R);
        }
        // gelu(agg), all types in one launch (contiguous)
        gelu4_kernel<<<((int)(NT * HIDF / 4) + 255) / 256, 256, 0, stream>>>(agg0, (int)(NT * HIDF / 4));
        // hg = sigmoid(skip)*(gelu(agg) @ aw + ab) + (1-sigmoid(skip))*h
        {
            GemmDescArr<3> D;
            for (int t = 0; t < 3; t++) {
                const size_t wo = (size_t)(l * 3 + t) * HIDF * HIDF;
                const size_t bo = (size_t)(l * 3 + t) * HIDF;
                float* aggt = (t == 0) ? agg0 : (t == 1 ? agg1 : agg2);
                D.d[t] = { aggt, aw + wo, hgptr[t], ab + bo, skip + l * 3 + t, hptr[t], Ns[t] };
            }
            gemm_nn_batched<3, M_SKIP, false><<<dim3(4, 64, 3), 256, 0, stream>>>(D, HIDF, HIDF);
        }

        // cross attention: types 1,2 attend to participants (h0)
        for (int t = 1; t <= 2; t++) {
            const int c = t - 1, Nq = Ns[t];
            {
                GemmDescArr<3> D;
                D.d[0] = { hptr[t], ca_qw + (size_t)c * 65536, caq, ca_qb + c * HIDF, nullptr, nullptr, Nq };
                D.d[1] = { h0,      ca_kw + (size_t)c * 65536, cak, ca_kb + c * HIDF, nullptr, nullptr, N0 };
                D.d[2] = { h0,      ca_vw + (size_t)c * 65536, cav, ca_vb + c * HIDF, nullptr, nullptr, N0 };
                gemm_nn_batched<3, M_STORE, false><<<dim3(4, Nq / 64, 3), 256, 0, stream>>>(D, HIDF, HIDF);
            }
            cast_split_kernel<<<(Nq * HIDF + 255) / 256, 256, 0, stream>>>(caq, qh16, Nq, ATT_SCALE);
            cast_split_kernel<<<(N0 * HIDF + 255) / 256, 256, 0, stream>>>(cak, kh16, N0, 1.0f);
            transposeV_kernel<<<dim3(N0 / 64, NHEAD), 256, 0, stream>>>(cav, vT16, N0);
            flash_ca<<<dim3(Nq / 64, NHEAD), 256, 0, stream>>>(qh16, kh16, vT16, cao, Nq, N0);
            gemm_simple<<<dim3(4, Nq / 64), 256, 0, stream>>>(cao, HIDF, ca_ow + (size_t)c * 65536,
                                                              hgptr[t], ca_ob + c * HIDF, Nq, HIDF, HIDF, M_ADD);
        }

        // h = gelu(LN(h + hg))
        for (int t = 0; t < 3; t++)
            ln_gelu_kernel<<<Ns[t], 256, 0, stream>>>(hptr[t], hgptr[t], ln_g + t * HIDF, ln_b + t * HIDF);
    }

    // ---- output projections (batched, N=128) ----
    {
        GemmDescArr<3> D;
        D.d[0] = { h0, outw + 0,     dout,                            outb,       nullptr, nullptr, N0 };
        D.d[1] = { h1, outw + 32768, dout + (size_t)N0 * OUTF,        outb + 128, nullptr, nullptr, N1 };
        D.d[2] = { h2, outw + 65536, dout + (size_t)(N0 + N1) * OUTF, outb + 256, nullptr, nullptr, N2 };
        gemm_nn_batched<3, M_STORE, false><<<dim3(2, 64, 3), 256, 0, stream>>>(D, OUTF, HIDF);
    }
}

// Round 4
// 1625.180 us; speedup vs baseline: 1.9240x; 1.1595x over previous
//
#include <hip/hip_runtime.h>
#include <math.h>
#include <stdint.h>
#include <stddef.h>

typedef unsigned short ushort_t;
typedef short  bf16x8 __attribute__((ext_vector_type(8)));
typedef float  f32x4  __attribute__((ext_vector_type(4)));

// ---------------------------------------------------------------------------
static constexpr int NHEAD = 4;
static constexpr int HDIM  = 64;
static constexpr int HIDF  = 256;   // NHEAD*HDIM
static constexpr int OUTF  = 128;
static constexpr int N0 = 2048, N1 = 4096, N2 = 3072;   // participant, gene, metabolite
static constexpr int E_PG = 250000, E_GP = 250000, E_PM = 200000, E_MP = 200000;
static constexpr float ATT_SCALE = 0.125f;              // 1/sqrt(64)

enum { M_STORE = 0, M_ADD = 1, M_SKIP = 2 };

__device__ __forceinline__ float gelu_exact(float x) {
    return 0.5f * x * (1.0f + erff(x * 0.7071067811865476f));
}
__device__ __forceinline__ ushort_t f2bf(float f) {       // RNE fp32->bf16
    unsigned x = __float_as_uint(f);
    return (ushort_t)((x + 0x7fffu + ((x >> 16) & 1u)) >> 16);
}
__device__ __forceinline__ float bflo(unsigned u) { return __uint_as_float(u << 16); }
__device__ __forceinline__ float bfhi(unsigned u) { return __uint_as_float(u & 0xffff0000u); }

// ---------------------------------------------------------------------------
// Simple fp32 NN GEMM: C[M,N] = A[M,K] @ B[K,N] + bias (mode STORE/ADD).
__global__ __launch_bounds__(256) void gemm_simple(
    const float* __restrict__ A, int lda, const float* __restrict__ B,
    float* __restrict__ C, const float* __restrict__ bias,
    int M, int N, int K, int mode)
{
    __shared__ float As[16][64];
    __shared__ float Bs[16][64];
    const int tid = threadIdx.x;
    const int tx = tid & 15, ty = tid >> 4;
    const int bm = blockIdx.y << 6, bn = blockIdx.x << 6;
    const int alr = tid >> 2, alc = (tid & 3) << 2;
    const int blr = tid >> 4, blc = (tid & 15) << 2;

    float acc[4][4] = {};
    for (int k0 = 0; k0 < K; k0 += 16) {
        float4 av = *(const float4*)(A + (size_t)(bm + alr) * lda + k0 + alc);
        As[alc + 0][alr] = av.x; As[alc + 1][alr] = av.y;
        As[alc + 2][alr] = av.z; As[alc + 3][alr] = av.w;
        float4 bv = *(const float4*)(B + (size_t)(k0 + blr) * N + bn + blc);
        *(float4*)&Bs[blr][blc] = bv;
        __syncthreads();
#pragma unroll
        for (int kk = 0; kk < 16; kk++) {
            const float4 a4 = *(const float4*)&As[kk][ty << 2];
            const float4 b4 = *(const float4*)&Bs[kk][tx << 2];
            acc[0][0] = fmaf(a4.x, b4.x, acc[0][0]); acc[0][1] = fmaf(a4.x, b4.y, acc[0][1]);
            acc[0][2] = fmaf(a4.x, b4.z, acc[0][2]); acc[0][3] = fmaf(a4.x, b4.w, acc[0][3]);
            acc[1][0] = fmaf(a4.y, b4.x, acc[1][0]); acc[1][1] = fmaf(a4.y, b4.y, acc[1][1]);
            acc[1][2] = fmaf(a4.y, b4.z, acc[1][2]); acc[1][3] = fmaf(a4.y, b4.w, acc[1][3]);
            acc[2][0] = fmaf(a4.z, b4.x, acc[2][0]); acc[2][1] = fmaf(a4.z, b4.y, acc[2][1]);
            acc[2][2] = fmaf(a4.z, b4.z, acc[2][2]); acc[2][3] = fmaf(a4.z, b4.w, acc[2][3]);
            acc[3][0] = fmaf(a4.w, b4.x, acc[3][0]); acc[3][1] = fmaf(a4.w, b4.y, acc[3][1]);
            acc[3][2] = fmaf(a4.w, b4.z, acc[3][2]); acc[3][3] = fmaf(a4.w, b4.w, acc[3][3]);
        }
        __syncthreads();
    }
#pragma unroll
    for (int i = 0; i < 4; i++) {
        const int mrow = bm + (ty << 2) + i;
        float* crow = C + (size_t)mrow * N + bn + (tx << 2);
#pragma unroll
        for (int j = 0; j < 4; j++) {
            float v = acc[i][j] + bias[bn + (tx << 2) + j];
            if (mode == M_ADD) crow[j] += v; else crow[j] = v;
        }
    }
}

// ---------------------------------------------------------------------------
// Descriptor-batched NN GEMM (A[M,256/K] @ B[K,N]); B16 => C is bf16.
struct GemmDesc {
    const float* A; const float* B; float* C;
    const float* bias; const float* skipv; const float* H;
    int M;
};
template <int NZ> struct GemmDescArr { GemmDesc d[NZ]; };

template <int NZ, int MODE, bool B16>
__global__ __launch_bounds__(256) void gemm_nn_batched(GemmDescArr<NZ> P, int N, int K)
{
    const GemmDesc g = P.d[blockIdx.z];
    const int bm = blockIdx.y << 6;
    if (bm >= g.M) return;
    const int bn = blockIdx.x << 6;

    __shared__ float As[16][64];
    __shared__ float Bs[16][64];
    const int tid = threadIdx.x;
    const int tx = tid & 15, ty = tid >> 4;
    const int alr = tid >> 2, alc = (tid & 3) << 2;
    const int blr = tid >> 4, blc = (tid & 15) << 2;

    float acc[4][4] = {};
    for (int k0 = 0; k0 < K; k0 += 16) {
        float4 av = *(const float4*)(g.A + (size_t)(bm + alr) * K + k0 + alc);
        As[alc + 0][alr] = av.x; As[alc + 1][alr] = av.y;
        As[alc + 2][alr] = av.z; As[alc + 3][alr] = av.w;
        float4 bv = *(const float4*)(g.B + (size_t)(k0 + blr) * N + bn + blc);
        *(float4*)&Bs[blr][blc] = bv;
        __syncthreads();
#pragma unroll
        for (int kk = 0; kk < 16; kk++) {
            const float4 a4 = *(const float4*)&As[kk][ty << 2];
            const float4 b4 = *(const float4*)&Bs[kk][tx << 2];
            acc[0][0] = fmaf(a4.x, b4.x, acc[0][0]); acc[0][1] = fmaf(a4.x, b4.y, acc[0][1]);
            acc[0][2] = fmaf(a4.x, b4.z, acc[0][2]); acc[0][3] = fmaf(a4.x, b4.w, acc[0][3]);
            acc[1][0] = fmaf(a4.y, b4.x, acc[1][0]); acc[1][1] = fmaf(a4.y, b4.y, acc[1][1]);
            acc[1][2] = fmaf(a4.y, b4.z, acc[1][2]); acc[1][3] = fmaf(a4.y, b4.w, acc[1][3]);
            acc[2][0] = fmaf(a4.z, b4.x, acc[2][0]); acc[2][1] = fmaf(a4.z, b4.y, acc[2][1]);
            acc[2][2] = fmaf(a4.z, b4.z, acc[2][2]); acc[2][3] = fmaf(a4.z, b4.w, acc[2][3]);
            acc[3][0] = fmaf(a4.w, b4.x, acc[3][0]); acc[3][1] = fmaf(a4.w, b4.y, acc[3][1]);
            acc[3][2] = fmaf(a4.w, b4.z, acc[3][2]); acc[3][3] = fmaf(a4.w, b4.w, acc[3][3]);
        }
        __syncthreads();
    }

    float gblend = 0.f, hblend = 0.f;
    if (MODE == M_SKIP) {
        const float sv = g.skipv[0];
        gblend = 1.f / (1.f + expf(-sv));
        hblend = 1.f - gblend;
    }
#pragma unroll
    for (int i = 0; i < 4; i++) {
        const int mrow = bm + (ty << 2) + i;
#pragma unroll
        for (int j = 0; j < 4; j++) {
            const int col = bn + (tx << 2) + j;
            float v = acc[i][j] + g.bias[col];
            if (B16) {
                ((ushort_t*)g.C)[(size_t)mrow * N + col] = f2bf(v);
            } else if (MODE == M_SKIP) {
                g.C[(size_t)mrow * N + col] =
                    gblend * v + hblend * g.H[(size_t)mrow * N + col];
            } else {
                g.C[(size_t)mrow * N + col] = v;
            }
        }
    }
}

// ---------------------------------------------------------------------------
// Per-node, per-head 64x64 transforms (batched descriptors, optional 2-term):
//  trw=0: Y[n,h,f] = sum_d X1[n,h,d] W1[h,d,f]  (+ X2 W2)
//  trw=1: Y[n,h,d] = sum_f X1[n,h,f] W1[h,d,f]           (Q' trick)
struct RelDesc2 { const float* X1; const float* W1; const float* X2; const float* W2;
                  float* Y; int rows; int trw; };
template <int ND> struct RelDesc2Arr { RelDesc2 d[ND]; };

template <int ND>
__global__ __launch_bounds__(256) void rel2_kernel(RelDesc2Arr<ND> P)
{
    const RelDesc2 g = P.d[blockIdx.z];
    const int n0 = blockIdx.x << 4;
    if (n0 >= g.rows) return;
    __shared__ float Ws1[64][65];
    __shared__ float Ws2[64][65];
    __shared__ float Xs1[16][64];
    __shared__ float Xs2[16][64];
    const int h = blockIdx.y, tid = threadIdx.x;
    const bool two = (g.X2 != nullptr);
    const float* W1h = g.W1 + (h << 12);
    for (int i = tid; i < 4096; i += 256) {
        const float wv = W1h[i];
        if (g.trw) Ws1[i & 63][i >> 6] = wv; else Ws1[i >> 6][i & 63] = wv;
    }
    for (int i = tid; i < 1024; i += 256)
        Xs1[i >> 6][i & 63] = g.X1[(size_t)(n0 + (i >> 6)) * HIDF + (h << 6) + (i & 63)];
    if (two) {
        const float* W2h = g.W2 + (h << 12);
        for (int i = tid; i < 4096; i += 256) {
            const float wv = W2h[i];
            if (g.trw) Ws2[i & 63][i >> 6] = wv; else Ws2[i >> 6][i & 63] = wv;
        }
        for (int i = tid; i < 1024; i += 256)
            Xs2[i >> 6][i & 63] = g.X2[(size_t)(n0 + (i >> 6)) * HIDF + (h << 6) + (i & 63)];
    }
    __syncthreads();
    const int r = tid >> 4, f0 = (tid & 15) << 2;
    float a0 = 0, a1 = 0, a2 = 0, a3 = 0;
#pragma unroll 8
    for (int d = 0; d < 64; d++) {
        const float x1 = Xs1[r][d];
        a0 = fmaf(x1, Ws1[d][f0 + 0], a0);
        a1 = fmaf(x1, Ws1[d][f0 + 1], a1);
        a2 = fmaf(x1, Ws1[d][f0 + 2], a2);
        a3 = fmaf(x1, Ws1[d][f0 + 3], a3);
    }
    if (two) {
#pragma unroll 8
        for (int d = 0; d < 64; d++) {
            const float x2 = Xs2[r][d];
            a0 = fmaf(x2, Ws2[d][f0 + 0], a0);
            a1 = fmaf(x2, Ws2[d][f0 + 1], a1);
            a2 = fmaf(x2, Ws2[d][f0 + 2], a2);
            a3 = fmaf(x2, Ws2[d][f0 + 3], a3);
        }
    }
    const size_t yb = (size_t)(n0 + r) * HIDF + (h << 6) + f0;
    g.Y[yb] = a0; g.Y[yb + 1] = a1; g.Y[yb + 2] = a2; g.Y[yb + 3] = a3;
}

// ---------------------------------------------------------------------------
// Counting sort by destination
__global__ void count_kernel(const int* __restrict__ dst, int E, int* __restrict__ cnt)
{
    int i = blockIdx.x * 256 + threadIdx.x;
    if (i < E) atomicAdd(&cnt[dst[i]], 1);
}

__global__ __launch_bounds__(256) void scan_kernel(int* __restrict__ cntcur, int N, int* __restrict__ off)
{
    __shared__ int sums[256];
    const int tid = threadIdx.x;
    const int base = tid * 16;
    int vals[16];
    int s = 0;
#pragma unroll
    for (int j = 0; j < 16; j++) {
        int idx = base + j;
        int c = (idx < N) ? cntcur[idx] : 0;
        vals[j] = s; s += c;
    }
    sums[tid] = s;
    __syncthreads();
    for (int d = 1; d < 256; d <<= 1) {
        int v = (tid >= d) ? sums[tid - d] : 0;
        __syncthreads();
        sums[tid] += v;
        __syncthreads();
    }
    int prefix = (tid > 0) ? sums[tid - 1] : 0;
#pragma unroll
    for (int j = 0; j < 16; j++) {
        int idx = base + j;
        if (idx < N) { int v = prefix + vals[j]; off[idx] = v; cntcur[idx] = v; }
    }
    if (tid == 255) off[N] = sums[255];
}

__global__ void scatter_kernel(const int* __restrict__ src, const int* __restrict__ dst, int E,
                               int* __restrict__ cur, int* __restrict__ esrc)
{
    int i = blockIdx.x * 256 + threadIdx.x;
    if (i < E) esrc[atomicAdd(&cur[dst[i]], 1)] = src[i];
}

// ---------------------------------------------------------------------------
// HGT edge attention v2 — latency-chain broken via explicit MLP batching.
// Per (dst, head) wave: chunks of 64 edges.
//   phase 1: lane=edge, 64-dim dot (8 independent 16B gather loads).
//   phase 2: wave max only (lsum deferred to end as per-lane partial).
//   phase 3: lane=(edge-parity, dim-pair); 16-edge batches: 8 LDS reads +
//            8 independent 4B V-loads issued before fmas; even/odd sub-accs.
__device__ __forceinline__ void edge_seg_v2(
    const float* __restrict__ qsh,        // this wave's 64-float Q' row (LDS)
    float2* __restrict__ wssh,            // this wave's 64-entry {w, srcbits} (LDS)
    const int* __restrict__ es, int i0, int i1,
    const ushort_t* __restrict__ Kt, const ushort_t* __restrict__ Vt,
    float pscale, int lane, int koff,
    float& m, float& plsum, float2& acc)
{
    const int epar = lane >> 5;                 // edge parity handled by this lane
    const int dpair = (lane & 31) << 1;         // dim pair owned by this lane
    for (int c = i0; c < i1; c += 64) {
        const int e = c + lane;
        const bool valid = e < i1;
        const int sidx = valid ? es[e] : 0;
        // ---- phase 1: dot(Q', K[sidx]) ----
        const uint4* kr = (const uint4*)(Kt + ((size_t)sidx << 8) + koff);
        float d0 = 0.f, d1 = 0.f;
#pragma unroll
        for (int u = 0; u < 8; u++) {
            const uint4 kv = kr[u];
            const float4 qa = *(const float4*)(qsh + (u << 3));
            const float4 qb = *(const float4*)(qsh + (u << 3) + 4);
            float dd = (u & 1) ? d1 : d0;
            dd = fmaf(bflo(kv.x), qa.x, dd); dd = fmaf(bfhi(kv.x), qa.y, dd);
            dd = fmaf(bflo(kv.y), qa.z, dd); dd = fmaf(bfhi(kv.y), qa.w, dd);
            dd = fmaf(bflo(kv.z), qb.x, dd); dd = fmaf(bfhi(kv.z), qb.y, dd);
            dd = fmaf(bflo(kv.w), qb.z, dd); dd = fmaf(bfhi(kv.w), qb.w, dd);
            if (u & 1) d1 = dd; else d0 = dd;
        }
        const float a = valid ? (d0 + d1) * pscale : -INFINITY;
        // ---- phase 2: chunk max + online rescale (lsum deferred per-lane) ----
        float cm = a;
#pragma unroll
        for (int o = 32; o; o >>= 1) cm = fmaxf(cm, __shfl_xor(cm, o));
        const float mn = fmaxf(m, cm);
        const float sc = (m == -INFINITY) ? 0.f : expf(m - mn);
        const float w = valid ? expf(a - mn) : 0.f;
        plsum = plsum * sc + w;
        m = mn;
        wssh[lane] = make_float2(w, __int_as_float(sidx));
        // ---- phase 3: batched V accumulate ----
        acc.x *= sc; acc.y *= sc;
        float2 aE = make_float2(0.f, 0.f), aO = make_float2(0.f, 0.f);
#pragma unroll
        for (int b = 0; b < 64; b += 16) {
            float2 we[8];
            unsigned vv[8];
#pragma unroll
            for (int j = 0; j < 8; j++) we[j] = wssh[b + (j << 1) + epar];
#pragma unroll
            for (int j = 0; j < 8; j++) {
                const int sj = __float_as_int(we[j].y);
                vv[j] = *(const unsigned*)(Vt + (((size_t)sj) << 8) + koff + dpair);
            }
#pragma unroll
            for (int j = 0; j < 8; j++) {
                const float wj = we[j].x;
                if (j & 1) { aO.x = fmaf(wj, bflo(vv[j]), aO.x);
                             aO.y = fmaf(wj, bfhi(vv[j]), aO.y); }
                else       { aE.x = fmaf(wj, bflo(vv[j]), aE.x);
                             aE.y = fmaf(wj, bfhi(vv[j]), aE.y); }
            }
        }
        acc.x += aE.x + aO.x;
        acc.y += aE.y + aO.y;
    }
}

// Single-relation dst types (gene, metabolite): 4 waves = 4 heads.
__global__ __launch_bounds__(256) void edge_attn_single(
    const float* __restrict__ Qp, const int* __restrict__ off, const int* __restrict__ es,
    const ushort_t* __restrict__ Kt, const ushort_t* __restrict__ Vt,
    const float* __restrict__ prel, int r, float* __restrict__ out)
{
    __shared__ float qsh[NHEAD][64];
    __shared__ float2 wssh[NHEAD][64];
    const int dstn = blockIdx.x, tid = threadIdx.x, lane = tid & 63, h = tid >> 6;
    const int koff = h << 6;
    qsh[h][lane] = Qp[(size_t)dstn * HIDF + koff + lane];
    const float ps = prel[(r << 2) + h] * ATT_SCALE;
    float m = -INFINITY, plsum = 0.f;
    float2 acc = make_float2(0.f, 0.f);
    edge_seg_v2(qsh[h], wssh[h], es, off[dstn], off[dstn + 1], Kt, Vt, ps, lane, koff,
                m, plsum, acc);
    acc.x += __shfl_xor(acc.x, 32);      // merge edge-parity halves
    acc.y += __shfl_xor(acc.y, 32);
    float l = plsum;
#pragma unroll
    for (int o = 32; o; o >>= 1) l += __shfl_xor(l, o);
    const float inv = (l > 0.f) ? 1.f / l : 0.f;
    if (lane < 32)
        *(float2*)(out + (size_t)dstn * HIDF + koff + ((lane & 31) << 1)) =
            make_float2(acc.x * inv, acc.y * inv);
}

// Dual-relation dst type (participant): 8 waves = 2 relations x 4 heads,
// merged by a flash-style (m,l) combine; per-relation V-sums kept separate
// (common softmax denominator, m_rel applied later per relation).
__global__ __launch_bounds__(512) void edge_attn_dual(
    const float* __restrict__ QpA, const float* __restrict__ QpB,
    const int* __restrict__ offA, const int* __restrict__ esA,
    const int* __restrict__ offB, const int* __restrict__ esB,
    const ushort_t* __restrict__ KA, const ushort_t* __restrict__ VA,
    const ushort_t* __restrict__ KB, const ushort_t* __restrict__ VB,
    const float* __restrict__ prel, int ra, int rb,
    float* __restrict__ outA, float* __restrict__ outB)
{
    __shared__ float qsh[8][64];
    __shared__ float2 wssh[8][64];
    __shared__ float mS[8], lS[8];
    const int dstn = blockIdx.x, tid = threadIdx.x, lane = tid & 63, wv = tid >> 6;
    const int rel = wv >> 2, h = wv & 3, koff = h << 6;
    const float* Qp = rel ? QpB : QpA;
    qsh[wv][lane] = Qp[(size_t)dstn * HIDF + koff + lane];
    const float ps = prel[((rel ? rb : ra) << 2) + h] * ATT_SCALE;
    float m = -INFINITY, plsum = 0.f;
    float2 acc = make_float2(0.f, 0.f);
    if (rel == 0)
        edge_seg_v2(qsh[wv], wssh[wv], esA, offA[dstn], offA[dstn + 1], KA, VA, ps,
                    lane, koff, m, plsum, acc);
    else
        edge_seg_v2(qsh[wv], wssh[wv], esB, offB[dstn], offB[dstn + 1], KB, VB, ps,
                    lane, koff, m, plsum, acc);
    acc.x += __shfl_xor(acc.x, 32);
    acc.y += __shfl_xor(acc.y, 32);
    float l = plsum;
#pragma unroll
    for (int o = 32; o; o >>= 1) l += __shfl_xor(l, o);
    if (lane == 0) { mS[wv] = m; lS[wv] = l; }
    __syncthreads();
    const float mo = mS[wv ^ 4], lo = lS[wv ^ 4];
    const float mn = fmaxf(m, mo);
    const float s  = (m  == -INFINITY) ? 0.f : expf(m - mn);
    const float so = (mo == -INFINITY) ? 0.f : expf(mo - mn);
    const float L = l * s + lo * so;
    const float factor = (L > 0.f) ? s / L : 0.f;
    float* out = rel ? outB : outA;
    if (lane < 32)
        *(float2*)(out + (size_t)dstn * HIDF + koff + ((lane & 31) << 1)) =
            make_float2(acc.x * factor, acc.y * factor);
}

// ---------------------------------------------------------------------------
__global__ void gelu4_kernel(float* __restrict__ x, int n4)
{
    int i = blockIdx.x * 256 + threadIdx.x;
    if (i < n4) {
        float4 v = ((float4*)x)[i];
        v.x = gelu_exact(v.x); v.y = gelu_exact(v.y);
        v.z = gelu_exact(v.z); v.w = gelu_exact(v.w);
        ((float4*)x)[i] = v;
    }
}

// [N][256] fp32 -> [4][N][64] bf16 (optionally scaled)
__global__ void cast_split_kernel(const float* __restrict__ in, ushort_t* __restrict__ out,
                                  int Nrows, float scale)
{
    int i = blockIdx.x * 256 + threadIdx.x;
    if (i < Nrows * HIDF) {
        const int n = i >> 8, c = i & 255, hh = c >> 6, d = c & 63;
        out[((size_t)hh * Nrows + n) * 64 + d] = f2bf(in[i] * scale);
    }
}

// [N][256] fp32 -> [4][64][N] bf16 (per-head transpose)
__global__ __launch_bounds__(256) void transposeV_kernel(
    const float* __restrict__ in, ushort_t* __restrict__ out, int Nrows)
{
    __shared__ float Ls[64][65];
    const int h = blockIdx.y, n0 = blockIdx.x << 6, tid = threadIdx.x;
    const int c = tid & 63, rq = tid >> 6;
    for (int rr = rq; rr < 64; rr += 4)
        Ls[rr][c] = in[(size_t)(n0 + rr) * HIDF + (h << 6) + c];
    __syncthreads();
    for (int dd = rq; dd < 64; dd += 4)
        out[((size_t)(h * 64 + dd)) * Nrows + n0 + c] = f2bf(Ls[c][dd]);
}

// ---------------------------------------------------------------------------
// Flash cross-attention: O[q, h*64+d] = softmax(Q K^T) V, bf16 MFMA.
// Grid (Nq/64, 4 heads); 4 waves, each owns 16 q-rows; K/V read from L2.
__global__ __launch_bounds__(256) void flash_ca(
    const ushort_t* __restrict__ qh, const ushort_t* __restrict__ kh,
    const ushort_t* __restrict__ vT, float* __restrict__ O, int Nq, int Nk)
{
    __shared__ ushort_t Pl[4][16][72];
    const int head = blockIdx.y;
    const int q0 = blockIdx.x << 6;
    const int tid = threadIdx.x, wave = tid >> 6, lane = tid & 63;
    const int l15 = lane & 15, lg = lane >> 4;

    const ushort_t* qbase = qh + ((size_t)head * Nq + q0 + (wave << 4) + l15) * 64 + (lg << 3);
    const bf16x8 qa0 = *(const bf16x8*)qbase;
    const bf16x8 qa1 = *(const bf16x8*)(qbase + 32);
    const ushort_t* kbase = kh + (size_t)head * Nk * 64;
    const ushort_t* vbase = vT + (size_t)head * 64 * Nk;

    f32x4 o[4] = {{0,0,0,0},{0,0,0,0},{0,0,0,0},{0,0,0,0}};
    float m[4]    = {-INFINITY, -INFINITY, -INFINITY, -INFINITY};
    float lsum[4] = {0.f, 0.f, 0.f, 0.f};

    const int nkt = Nk >> 6;
    for (int kt = 0; kt < nkt; kt++) {
        const int k0 = kt << 6;
        f32x4 s[4] = {{0,0,0,0},{0,0,0,0},{0,0,0,0},{0,0,0,0}};
        const ushort_t* krow = kbase + ((size_t)(k0 + l15)) * 64 + (lg << 3);
#pragma unroll
        for (int ct = 0; ct < 4; ct++) {
            const bf16x8 b = *(const bf16x8*)(krow + (ct << 10));
            s[ct] = __builtin_amdgcn_mfma_f32_16x16x32_bf16(qa0, b, s[ct], 0, 0, 0);
        }
#pragma unroll
        for (int ct = 0; ct < 4; ct++) {
            const bf16x8 b = *(const bf16x8*)(krow + (ct << 10) + 32);
            s[ct] = __builtin_amdgcn_mfma_f32_16x16x32_bf16(qa1, b, s[ct], 0, 0, 0);
        }
        // online softmax over this 64-key tile (C layout: col=l15, row=lg*4+r)
        float tm[4], sc[4], ts[4];
#pragma unroll
        for (int r = 0; r < 4; r++)
            tm[r] = fmaxf(fmaxf(s[0][r], s[1][r]), fmaxf(s[2][r], s[3][r]));
#pragma unroll
        for (int off = 1; off <= 8; off <<= 1)
#pragma unroll
            for (int r = 0; r < 4; r++)
                tm[r] = fmaxf(tm[r], __shfl_xor(tm[r], off));
#pragma unroll
        for (int r = 0; r < 4; r++) {
            const float mn = fmaxf(m[r], tm[r]);
            sc[r] = expf(m[r] - mn);
            m[r] = mn;
            ts[r] = 0.f;
        }
#pragma unroll
        for (int ct = 0; ct < 4; ct++)
#pragma unroll
            for (int r = 0; r < 4; r++) {
                const float p = expf(s[ct][r] - m[r]);
                ts[r] += p;
                Pl[wave][(lg << 2) + r][(ct << 4) + l15] = f2bf(p);
            }
#pragma unroll
        for (int off = 1; off <= 8; off <<= 1)
#pragma unroll
            for (int r = 0; r < 4; r++)
                ts[r] += __shfl_xor(ts[r], off);
#pragma unroll
        for (int r = 0; r < 4; r++)
            lsum[r] = lsum[r] * sc[r] + ts[r];
#pragma unroll
        for (int vt = 0; vt < 4; vt++)
#pragma unroll
            for (int r = 0; r < 4; r++)
                o[vt][r] *= sc[r];
        // P fragments (same-wave LDS round-trip)
        const bf16x8 pa0 = *(const bf16x8*)&Pl[wave][l15][lg << 3];
        const bf16x8 pa1 = *(const bf16x8*)&Pl[wave][l15][32 + (lg << 3)];
        const ushort_t* vrow = vbase + (size_t)l15 * Nk + k0 + (lg << 3);
#pragma unroll
        for (int vt = 0; vt < 4; vt++) {
            const bf16x8 b = *(const bf16x8*)(vrow + (size_t)(vt << 4) * Nk);
            o[vt] = __builtin_amdgcn_mfma_f32_16x16x32_bf16(pa0, b, o[vt], 0, 0, 0);
        }
#pragma unroll
        for (int vt = 0; vt < 4; vt++) {
            const bf16x8 b = *(const bf16x8*)(vrow + (size_t)(vt << 4) * Nk + 32);
            o[vt] = __builtin_amdgcn_mfma_f32_16x16x32_bf16(pa1, b, o[vt], 0, 0, 0);
        }
    }
    float inv[4];
#pragma unroll
    for (int r = 0; r < 4; r++) inv[r] = 1.f / lsum[r];
#pragma unroll
    for (int vt = 0; vt < 4; vt++)
#pragma unroll
        for (int r = 0; r < 4; r++)
            O[(size_t)(q0 + (wave << 4) + (lg << 2) + r) * HIDF
              + (head << 6) + (vt << 4) + l15] = o[vt][r] * inv[r];
}

// ---------------------------------------------------------------------------
// Fused residual + LayerNorm + exact GELU (in-place update of h).
__global__ __launch_bounds__(256) void ln_gelu_kernel(
    float* __restrict__ h, const float* __restrict__ hg,
    const float* __restrict__ g, const float* __restrict__ b)
{
    __shared__ float t4[4];
    const int row = blockIdx.x, tid = threadIdx.x, lane = tid & 63, w = tid >> 6;
    const size_t idx = (size_t)row * HIDF + tid;
    const float x = h[idx] + hg[idx];
    float v = x;
#pragma unroll
    for (int o = 32; o; o >>= 1) v += __shfl_xor(v, o);
    if (lane == 0) t4[w] = v;
    __syncthreads();
    const float mean = (t4[0] + t4[1] + t4[2] + t4[3]) * (1.f / 256.f);
    __syncthreads();
    const float d = x - mean;
    v = d * d;
#pragma unroll
    for (int o = 32; o; o >>= 1) v += __shfl_xor(v, o);
    if (lane == 0) t4[w] = v;
    __syncthreads();
    const float var = (t4[0] + t4[1] + t4[2] + t4[3]) * (1.f / 256.f);
    const float y = d * rsqrtf(var + 1e-5f) * g[tid] + b[tid];
    h[idx] = gelu_exact(y);
}

// ---------------------------------------------------------------------------
extern "C" void kernel_launch(void* const* d_in, const int* in_sizes, int n_in,
                              void* d_out, int out_size, void* d_ws, size_t ws_size,
                              hipStream_t stream)
{
    (void)in_sizes; (void)n_in; (void)out_size; (void)ws_size;
    const float* x_p   = (const float*)d_in[0];
    const float* x_g   = (const float*)d_in[1];
    const float* x_m   = (const float*)d_in[2];
    const int*  src_pg = (const int*)d_in[3];
    const int*  dst_pg = (const int*)d_in[4];
    const int*  src_gp = (const int*)d_in[5];
    const int*  dst_gp = (const int*)d_in[6];
    const int*  src_pm = (const int*)d_in[7];
    const int*  dst_pm = (const int*)d_in[8];
    const int*  src_mp = (const int*)d_in[9];
    const int*  dst_mp = (const int*)d_in[10];
    const float* Win_p = (const float*)d_in[11];
    const float* bin_p = (const float*)d_in[12];
    const float* Win_g = (const float*)d_in[13];
    const float* bin_g = (const float*)d_in[14];
    const float* Win_m = (const float*)d_in[15];
    const float* bin_m = (const float*)d_in[16];
    const float* kw    = (const float*)d_in[17];
    const float* qw    = (const float*)d_in[18];
    const float* vw    = (const float*)d_in[19];
    const float* aw    = (const float*)d_in[20];
    const float* kb    = (const float*)d_in[21];
    const float* qb    = (const float*)d_in[22];
    const float* vb    = (const float*)d_in[23];
    const float* ab    = (const float*)d_in[24];
    const float* skip  = (const float*)d_in[25];
    const float* a_rel = (const float*)d_in[26];
    const float* m_rel = (const float*)d_in[27];
    const float* p_rel = (const float*)d_in[28];
    const float* ca_qw = (const float*)d_in[29];
    const float* ca_kw = (const float*)d_in[30];
    const float* ca_vw = (const float*)d_in[31];
    const float* ca_ow = (const float*)d_in[32];
    const float* ca_qb = (const float*)d_in[33];
    const float* ca_kb = (const float*)d_in[34];
    const float* ca_vb = (const float*)d_in[35];
    const float* ca_ob = (const float*)d_in[36];
    const float* ln_g  = (const float*)d_in[37];
    const float* ln_b  = (const float*)d_in[38];
    const float* outw  = (const float*)d_in[39];
    const float* outb  = (const float*)d_in[40];
    float* dout = (float*)d_out;

    // ---- workspace carve-up ----
    float* Wp = (float*)d_ws;
    size_t cursz = 0;
    auto alloc = [&](size_t n) -> float* {
        float* p = Wp + cursz; cursz += (n + 63) & ~(size_t)63; return p;
    };
    const size_t NT = N0 + N1 + N2;               // 9216
    float* h0  = alloc((size_t)N0 * HIDF);
    float* h1  = alloc((size_t)N1 * HIDF);
    float* h2  = alloc((size_t)N2 * HIDF);
    float* hg0 = alloc((size_t)N0 * HIDF);
    float* hg1 = alloc((size_t)N1 * HIDF);
    float* hg2 = alloc((size_t)N2 * HIDF);
    float* Q0  = alloc((size_t)N0 * HIDF);
    float* Q1  = alloc((size_t)N1 * HIDF);
    float* Q2  = alloc((size_t)N2 * HIDF);
    ushort_t* K16 = (ushort_t*)alloc(NT * HIDF / 2);
    ushort_t* V16 = (ushort_t*)alloc(NT * HIDF / 2);
    ushort_t* K16_0 = K16, *K16_1 = K16 + (size_t)N0 * HIDF, *K16_2 = K16 + (size_t)(N0 + N1) * HIDF;
    ushort_t* V16_0 = V16, *V16_1 = V16 + (size_t)N0 * HIDF, *V16_2 = V16 + (size_t)(N0 + N1) * HIDF;
    float* QpPool  = alloc((size_t)(N1 + N0 + N2 + N0) * HIDF);   // 11264 rows
    float* Qp0 = QpPool;
    float* Qp1 = Qp0 + (size_t)N1 * HIDF;
    float* Qp2 = Qp1 + (size_t)N0 * HIDF;
    float* Qp3 = Qp2 + (size_t)N2 * HIDF;
    float* PartPool = alloc((size_t)(N0 + N0 + N1 + N2) * HIDF);  // 11264 rows
    float* pA0 = PartPool;
    float* pB0 = pA0 + (size_t)N0 * HIDF;
    float* p1  = pB0 + (size_t)N0 * HIDF;
    float* p2  = p1 + (size_t)N1 * HIDF;
    float* agg0 = alloc(NT * HIDF);
    float* agg1 = agg0 + (size_t)N0 * HIDF;
    float* agg2 = agg1 + (size_t)N1 * HIDF;
    // CA fp32 buffers alias Qp+Part pools (dead during cross-attention)
    float* caq = QpPool;
    float* cak = caq + (size_t)N1 * HIDF;
    float* cav = cak + (size_t)N0 * HIDF;
    float* cao = cav + (size_t)N0 * HIDF;
    // CA bf16 tables alias agg (dead during cross-attention)
    ushort_t* qh16 = (ushort_t*)agg0;
    ushort_t* kh16 = qh16 + (size_t)NHEAD * N1 * HDIM;
    ushort_t* vT16 = kh16 + (size_t)NHEAD * N0 * HDIM;
    int* es_gp = (int*)alloc(E_GP);
    int* es_mp = (int*)alloc(E_MP);
    int* es_pg = (int*)alloc(E_PG);
    int* es_pm = (int*)alloc(E_PM);
    int* off_gp = (int*)alloc(N0 + 1); int* cur_gp = (int*)alloc(N0);
    int* off_mp = (int*)alloc(N0 + 1); int* cur_mp = (int*)alloc(N0);
    int* off_pg = (int*)alloc(N1 + 1); int* cur_pg = (int*)alloc(N1);
    int* off_pm = (int*)alloc(N2 + 1); int* cur_pm = (int*)alloc(N2);

    // ---- counting-sort edges by destination (4 independent CSRs) ----
    hipMemsetAsync(cur_gp, 0, N0 * sizeof(int), stream);
    count_kernel<<<(E_GP + 255) / 256, 256, 0, stream>>>(dst_gp, E_GP, cur_gp);
    scan_kernel<<<1, 256, 0, stream>>>(cur_gp, N0, off_gp);
    scatter_kernel<<<(E_GP + 255) / 256, 256, 0, stream>>>(src_gp, dst_gp, E_GP, cur_gp, es_gp);

    hipMemsetAsync(cur_mp, 0, N0 * sizeof(int), stream);
    count_kernel<<<(E_MP + 255) / 256, 256, 0, stream>>>(dst_mp, E_MP, cur_mp);
    scan_kernel<<<1, 256, 0, stream>>>(cur_mp, N0, off_mp);
    scatter_kernel<<<(E_MP + 255) / 256, 256, 0, stream>>>(src_mp, dst_mp, E_MP, cur_mp, es_mp);

    hipMemsetAsync(cur_pg, 0, N1 * sizeof(int), stream);
    count_kernel<<<(E_PG + 255) / 256, 256, 0, stream>>>(dst_pg, E_PG, cur_pg);
    scan_kernel<<<1, 256, 0, stream>>>(cur_pg, N1, off_pg);
    scatter_kernel<<<(E_PG + 255) / 256, 256, 0, stream>>>(src_pg, dst_pg, E_PG, cur_pg, es_pg);

    hipMemsetAsync(cur_pm, 0, N2 * sizeof(int), stream);
    count_kernel<<<(E_PM + 255) / 256, 256, 0, stream>>>(dst_pm, E_PM, cur_pm);
    scan_kernel<<<1, 256, 0, stream>>>(cur_pm, N2, off_pm);
    scatter_kernel<<<(E_PM + 255) / 256, 256, 0, stream>>>(src_pm, dst_pm, E_PM, cur_pm, es_pm);

    // ---- input projections ----
    gemm_simple<<<dim3(HIDF / 64, N0 / 64), 256, 0, stream>>>(x_p, 512, Win_p, h0, bin_p, N0, HIDF, 512, M_STORE);
    gemm_simple<<<dim3(HIDF / 64, N1 / 64), 256, 0, stream>>>(x_g, 768, Win_g, h1, bin_g, N1, HIDF, 768, M_STORE);
    gemm_simple<<<dim3(HIDF / 64, N2 / 64), 256, 0, stream>>>(x_m, 384, Win_m, h2, bin_m, N2, HIDF, 384, M_STORE);

    float* hptr[3]  = { h0, h1, h2 };
    float* hgptr[3] = { hg0, hg1, hg2 };
    float* Qptr[3]  = { Q0, Q1, Q2 };
    ushort_t* Kp[3] = { K16_0, K16_1, K16_2 };
    ushort_t* Vp[3] = { V16_0, V16_1, V16_2 };
    const int Ns[3] = { N0, N1, N2 };

    for (int l = 0; l < 2; l++) {
        // Q projections (fp32) — feeds Q' transform
        {
            GemmDescArr<3> D;
            for (int t = 0; t < 3; t++) {
                const size_t wo = (size_t)(l * 3 + t) * HIDF * HIDF;
                const size_t bo = (size_t)(l * 3 + t) * HIDF;
                D.d[t] = { hptr[t], qw + wo, Qptr[t], qb + bo, nullptr, nullptr, Ns[t] };
            }
            gemm_nn_batched<3, M_STORE, false><<<dim3(4, 64, 3), 256, 0, stream>>>(D, HIDF, HIDF);
        }
        // K/V projections written directly as bf16 gather tables
        {
            GemmDescArr<6> D;
            for (int t = 0; t < 3; t++) {
                const size_t wo = (size_t)(l * 3 + t) * HIDF * HIDF;
                const size_t bo = (size_t)(l * 3 + t) * HIDF;
                D.d[t]     = { hptr[t], kw + wo, (float*)Kp[t], kb + bo, nullptr, nullptr, Ns[t] };
                D.d[3 + t] = { hptr[t], vw + wo, (float*)Vp[t], vb + bo, nullptr, nullptr, Ns[t] };
            }
            gemm_nn_batched<6, M_STORE, true><<<dim3(4, 64, 6), 256, 0, stream>>>(D, HIDF, HIDF);
        }
        // Q' = a_rel[h] @ Q per dst node (trw=1), 4 relations in one launch
        {
            const float* ar = a_rel + (size_t)l * 4 * 16384;
            RelDesc2Arr<4> R;
            R.d[0] = { Q1, ar + 0 * 16384, nullptr, nullptr, Qp0, N1, 1 };
            R.d[1] = { Q0, ar + 1 * 16384, nullptr, nullptr, Qp1, N0, 1 };
            R.d[2] = { Q2, ar + 2 * 16384, nullptr, nullptr, Qp2, N2, 1 };
            R.d[3] = { Q0, ar + 3 * 16384, nullptr, nullptr, Qp3, N0, 1 };
            rel2_kernel<4><<<dim3(N1 / 16, NHEAD, 4), 256, 0, stream>>>(R);
        }
        // segment-softmax edge attention (raw-V partial sums per relation)
        const float* prl = p_rel + (size_t)l * 16;
        edge_attn_dual<<<N0, 512, 0, stream>>>(Qp1, Qp3, off_gp, es_gp, off_mp, es_mp,
                                               K16_1, V16_1, K16_2, V16_2, prl, 1, 3, pA0, pB0);
        edge_attn_single<<<N1, 256, 0, stream>>>(Qp0, off_pg, es_pg, K16_0, V16_0, prl, 0, p1);
        edge_attn_single<<<N2, 256, 0, stream>>>(Qp2, off_pm, es_pm, K16_0, V16_0, prl, 2, p2);
        // agg = sum_r partial_r @ m_rel[r]
        {
            const float* mr = m_rel + (size_t)l * 4 * 16384;
            RelDesc2Arr<3> R;
            R.d[0] = { pA0, mr + 1 * 16384, pB0, mr + 3 * 16384, agg0, N0, 0 };
            R.d[1] = { p1,  mr + 0 * 16384, nullptr, nullptr,    agg1, N1, 0 };
            R.d[2] = { p2,  mr + 2 * 16384, nullptr, nullptr,    agg2, N2, 0 };
            rel2_kernel<3><<<dim3(N1 / 16, NHEAD, 3), 256, 0, stream>>>(R);
        }
        // gelu(agg), all types in one launch (contiguous)
        gelu4_kernel<<<((int)(NT * HIDF / 4) + 255) / 256, 256, 0, stream>>>(agg0, (int)(NT * HIDF / 4));
        // hg = sigmoid(skip)*(gelu(agg) @ aw + ab) + (1-sigmoid(skip))*h
        {
            GemmDescArr<3> D;
            for (int t = 0; t < 3; t++) {
                const size_t wo = (size_t)(l * 3 + t) * HIDF * HIDF;
                const size_t bo = (size_t)(l * 3 + t) * HIDF;
                float* aggt = (t == 0) ? agg0 : (t == 1 ? agg1 : agg2);
                D.d[t] = { aggt, aw + wo, hgptr[t], ab + bo, skip + l * 3 + t, hptr[t], Ns[t] };
            }
            gemm_nn_batched<3, M_SKIP, false><<<dim3(4, 64, 3), 256, 0, stream>>>(D, HIDF, HIDF);
        }

        // cross attention: types 1,2 attend to participants (h0)
        for (int t = 1; t <= 2; t++) {
            const int c = t - 1, Nq = Ns[t];
            {
                GemmDescArr<3> D;
                D.d[0] = { hptr[t], ca_qw + (size_t)c * 65536, caq, ca_qb + c * HIDF, nullptr, nullptr, Nq };
                D.d[1] = { h0,      ca_kw + (size_t)c * 65536, cak, ca_kb + c * HIDF, nullptr, nullptr, N0 };
                D.d[2] = { h0,      ca_vw + (size_t)c * 65536, cav, ca_vb + c * HIDF, nullptr, nullptr, N0 };
                gemm_nn_batched<3, M_STORE, false><<<dim3(4, Nq / 64, 3), 256, 0, stream>>>(D, HIDF, HIDF);
            }
            cast_split_kernel<<<(Nq * HIDF + 255) / 256, 256, 0, stream>>>(caq, qh16, Nq, ATT_SCALE);
            cast_split_kernel<<<(N0 * HIDF + 255) / 256, 256, 0, stream>>>(cak, kh16, N0, 1.0f);
            transposeV_kernel<<<dim3(N0 / 64, NHEAD), 256, 0, stream>>>(cav, vT16, N0);
            flash_ca<<<dim3(Nq / 64, NHEAD), 256, 0, stream>>>(qh16, kh16, vT16, cao, Nq, N0);
            gemm_simple<<<dim3(4, Nq / 64), 256, 0, stream>>>(cao, HIDF, ca_ow + (size_t)c * 65536,
                                                              hgptr[t], ca_ob + c * HIDF, Nq, HIDF, HIDF, M_ADD);
        }

        // h = gelu(LN(h + hg))
        for (int t = 0; t < 3; t++)
            ln_gelu_kernel<<<Ns[t], 256, 0, stream>>>(hptr[t], hgptr[t], ln_g + t * HIDF, ln_b + t * HIDF);
    }

    // ---- output projections (batched, N=128) ----
    {
        GemmDescArr<3> D;
        D.d[0] = { h0, outw + 0,     dout,                            outb,       nullptr, nullptr, N0 };
        D.d[1] = { h1, outw + 32768, dout + (size_t)N0 * OUTF,        outb + 128, nullptr, nullptr, N1 };
        D.d[2] = { h2, outw + 65536, dout + (size_t)(N0 + N1) * OUTF, outb + 256, nullptr, nullptr, N2 };
        gemm_nn_batched<3, M_STORE, false><<<dim3(2, 64, 3), 256, 0, stream>>>(D, OUTF, HIDF);
    }
}

// Round 5
// 1344.055 us; speedup vs baseline: 2.3264x; 1.2092x over previous
//
#include <hip/hip_runtime.h>
#include <math.h>
#include <stdint.h>
#include <stddef.h>

typedef unsigned short ushort_t;
typedef short  bf16x8 __attribute__((ext_vector_type(8)));
typedef float  f32x4  __attribute__((ext_vector_type(4)));
typedef unsigned short us4 __attribute__((ext_vector_type(4)));

// ---------------------------------------------------------------------------
static constexpr int NHEAD = 4;
static constexpr int HDIM  = 64;
static constexpr int HIDF  = 256;   // NHEAD*HDIM
static constexpr int OUTF  = 128;
static constexpr int N0 = 2048, N1 = 4096, N2 = 3072;   // participant, gene, metabolite
static constexpr int E_PG = 250000, E_GP = 250000, E_PM = 200000, E_MP = 200000;
static constexpr float ATT_SCALE = 0.125f;              // 1/sqrt(64)

enum { M_STORE = 0, M_ADD = 1, M_SKIP = 2, M_B16 = 3 };

__device__ __forceinline__ float gelu_exact(float x) {
    return 0.5f * x * (1.0f + erff(x * 0.7071067811865476f));
}
__device__ __forceinline__ ushort_t f2bf(float f) {       // RNE fp32->bf16
    unsigned x = __float_as_uint(f);
    return (ushort_t)((x + 0x7fffu + ((x >> 16) & 1u)) >> 16);
}
__device__ __forceinline__ float bflo(unsigned u) { return __uint_as_float(u << 16); }
__device__ __forceinline__ float bfhi(unsigned u) { return __uint_as_float(u & 0xffff0000u); }

// ---------------------------------------------------------------------------
// MFMA GEMM: C[M,N] = epilogue(A16[M,K] @ BT16[N,K]^T + bias).
// Desc-batched via blockIdx.z. 64x64 tile, 4 waves (16 rows each), no LDS:
// A/B fragments read straight from L2-resident bf16 buffers.
struct MGemmDesc { const ushort_t* A; const ushort_t* BT; void* C;
                   const float* bias; const float* skipv; const float* H;
                   int M; int K; };
template <int NZ> struct MGemmDescArr { MGemmDesc d[NZ]; };

template <int NZ, int MODE>
__global__ __launch_bounds__(256) void gemm_mfma(MGemmDescArr<NZ> P, int N)
{
    const MGemmDesc g = P.d[blockIdx.z];
    const int bm = blockIdx.y << 6;
    if (bm >= g.M) return;
    const int bn = blockIdx.x << 6;
    const int tid = threadIdx.x, wave = tid >> 6, lane = tid & 63;
    const int l15 = lane & 15, lg = lane >> 4;
    const int K = g.K;
    const ushort_t* arow = g.A + (size_t)(bm + (wave << 4) + l15) * K + (lg << 3);
    const ushort_t* brow = g.BT + (size_t)(bn + l15) * K + (lg << 3);

    f32x4 acc[4] = {{0,0,0,0},{0,0,0,0},{0,0,0,0},{0,0,0,0}};
    for (int k0 = 0; k0 < K; k0 += 32) {
        const bf16x8 a = *(const bf16x8*)(arow + k0);
#pragma unroll
        for (int ct = 0; ct < 4; ct++) {
            const bf16x8 b = *(const bf16x8*)(brow + (size_t)(ct << 4) * K + k0);
            acc[ct] = __builtin_amdgcn_mfma_f32_16x16x32_bf16(a, b, acc[ct], 0, 0, 0);
        }
    }

    float gblend = 0.f, hblend = 0.f;
    if (MODE == M_SKIP) {
        const float sv = g.skipv[0];
        gblend = 1.f / (1.f + expf(-sv));
        hblend = 1.f - gblend;
    }
#pragma unroll
    for (int ct = 0; ct < 4; ct++) {
        const int col = bn + (ct << 4) + l15;
        const float bia = g.bias[col];
#pragma unroll
        for (int r = 0; r < 4; r++) {
            const int row = bm + (wave << 4) + (lg << 2) + r;
            const float v = acc[ct][r] + bia;
            if (MODE == M_B16) {
                ((ushort_t*)g.C)[(size_t)row * N + col] = f2bf(v);
            } else if (MODE == M_SKIP) {
                ((float*)g.C)[(size_t)row * N + col] =
                    gblend * v + hblend * g.H[(size_t)row * N + col];
            } else if (MODE == M_ADD) {
                ((float*)g.C)[(size_t)row * N + col] += v;
            } else {
                ((float*)g.C)[(size_t)row * N + col] = v;
            }
        }
    }
}

// ---------------------------------------------------------------------------
// Weight transpose+cast: W[K][N] fp32 -> WT[N][K] bf16 (desc-batched).
struct TWDesc { const float* W; ushort_t* WT; int K; int N; };
template <int ND> struct TWDescArr { TWDesc d[ND]; };

template <int ND>
__global__ __launch_bounds__(256) void transW_kernel(TWDescArr<ND> P)
{
    const TWDesc g = P.d[blockIdx.z];
    const int k0 = blockIdx.x << 6, n0 = blockIdx.y << 6;
    if (k0 >= g.K || n0 >= g.N) return;
    __shared__ float Ls[64][65];
    const int tid = threadIdx.x, c = tid & 63, rq = tid >> 6;
    for (int rr = rq; rr < 64; rr += 4)
        Ls[rr][c] = g.W[(size_t)(k0 + rr) * g.N + n0 + c];
    __syncthreads();
    for (int nn = rq; nn < 64; nn += 4)
        g.WT[(size_t)(n0 + nn) * g.K + k0 + c] = f2bf(Ls[c][nn]);
}

// fp32 -> bf16 flat cast (optionally with exact GELU first)
template <bool GELU>
__global__ void cast_bf16_kernel(const float* __restrict__ in, ushort_t* __restrict__ out, int n4)
{
    int i = blockIdx.x * 256 + threadIdx.x;
    if (i < n4) {
        float4 v = ((const float4*)in)[i];
        if (GELU) { v.x = gelu_exact(v.x); v.y = gelu_exact(v.y);
                    v.z = gelu_exact(v.z); v.w = gelu_exact(v.w); }
        us4 o;
        o[0] = f2bf(v.x); o[1] = f2bf(v.y); o[2] = f2bf(v.z); o[3] = f2bf(v.w);
        *(us4*)(out + (size_t)i * 4) = o;
    }
}

// ---------------------------------------------------------------------------
// Per-node, per-head 64x64 transforms (batched descriptors, optional 2-term):
//  trw=0: Y[n,h,f] = sum_d X1[n,h,d] W1[h,d,f]  (+ X2 W2)
//  trw=1: Y[n,h,d] = sum_f X1[n,h,f] W1[h,d,f]           (Q' trick)
struct RelDesc2 { const float* X1; const float* W1; const float* X2; const float* W2;
                  float* Y; int rows; int trw; };
template <int ND> struct RelDesc2Arr { RelDesc2 d[ND]; };

template <int ND>
__global__ __launch_bounds__(256) void rel2_kernel(RelDesc2Arr<ND> P)
{
    const RelDesc2 g = P.d[blockIdx.z];
    const int n0 = blockIdx.x << 4;
    if (n0 >= g.rows) return;
    __shared__ float Ws1[64][65];
    __shared__ float Ws2[64][65];
    __shared__ float Xs1[16][64];
    __shared__ float Xs2[16][64];
    const int h = blockIdx.y, tid = threadIdx.x;
    const bool two = (g.X2 != nullptr);
    const float* W1h = g.W1 + (h << 12);
    for (int i = tid; i < 4096; i += 256) {
        const float wv = W1h[i];
        if (g.trw) Ws1[i & 63][i >> 6] = wv; else Ws1[i >> 6][i & 63] = wv;
    }
    for (int i = tid; i < 1024; i += 256)
        Xs1[i >> 6][i & 63] = g.X1[(size_t)(n0 + (i >> 6)) * HIDF + (h << 6) + (i & 63)];
    if (two) {
        const float* W2h = g.W2 + (h << 12);
        for (int i = tid; i < 4096; i += 256) {
            const float wv = W2h[i];
            if (g.trw) Ws2[i & 63][i >> 6] = wv; else Ws2[i >> 6][i & 63] = wv;
        }
        for (int i = tid; i < 1024; i += 256)
            Xs2[i >> 6][i & 63] = g.X2[(size_t)(n0 + (i >> 6)) * HIDF + (h << 6) + (i & 63)];
    }
    __syncthreads();
    const int r = tid >> 4, f0 = (tid & 15) << 2;
    float a0 = 0, a1 = 0, a2 = 0, a3 = 0;
#pragma unroll 8
    for (int d = 0; d < 64; d++) {
        const float x1 = Xs1[r][d];
        a0 = fmaf(x1, Ws1[d][f0 + 0], a0);
        a1 = fmaf(x1, Ws1[d][f0 + 1], a1);
        a2 = fmaf(x1, Ws1[d][f0 + 2], a2);
        a3 = fmaf(x1, Ws1[d][f0 + 3], a3);
    }
    if (two) {
#pragma unroll 8
        for (int d = 0; d < 64; d++) {
            const float x2 = Xs2[r][d];
            a0 = fmaf(x2, Ws2[d][f0 + 0], a0);
            a1 = fmaf(x2, Ws2[d][f0 + 1], a1);
            a2 = fmaf(x2, Ws2[d][f0 + 2], a2);
            a3 = fmaf(x2, Ws2[d][f0 + 3], a3);
        }
    }
    const size_t yb = (size_t)(n0 + r) * HIDF + (h << 6) + f0;
    g.Y[yb] = a0; g.Y[yb + 1] = a1; g.Y[yb + 2] = a2; g.Y[yb + 3] = a3;
}

// ---------------------------------------------------------------------------
// Counting sort by destination
__global__ void count_kernel(const int* __restrict__ dst, int E, int* __restrict__ cnt)
{
    int i = blockIdx.x * 256 + threadIdx.x;
    if (i < E) atomicAdd(&cnt[dst[i]], 1);
}

__global__ __launch_bounds__(256) void scan_kernel(int* __restrict__ cntcur, int N, int* __restrict__ off)
{
    __shared__ int sums[256];
    const int tid = threadIdx.x;
    const int base = tid * 16;
    int vals[16];
    int s = 0;
#pragma unroll
    for (int j = 0; j < 16; j++) {
        int idx = base + j;
        int c = (idx < N) ? cntcur[idx] : 0;
        vals[j] = s; s += c;
    }
    sums[tid] = s;
    __syncthreads();
    for (int d = 1; d < 256; d <<= 1) {
        int v = (tid >= d) ? sums[tid - d] : 0;
        __syncthreads();
        sums[tid] += v;
        __syncthreads();
    }
    int prefix = (tid > 0) ? sums[tid - 1] : 0;
#pragma unroll
    for (int j = 0; j < 16; j++) {
        int idx = base + j;
        if (idx < N) { int v = prefix + vals[j]; off[idx] = v; cntcur[idx] = v; }
    }
    if (tid == 255) off[N] = sums[255];
}

__global__ void scatter_kernel(const int* __restrict__ src, const int* __restrict__ dst, int E,
                               int* __restrict__ cur, int* __restrict__ esrc)
{
    int i = blockIdx.x * 256 + threadIdx.x;
    if (i < E) esrc[atomicAdd(&cur[dst[i]], 1)] = src[i];
}

// ---------------------------------------------------------------------------
// HGT edge attention (latency-chain broken via explicit MLP batching).
__device__ __forceinline__ void edge_seg_v2(
    const float* __restrict__ qsh,
    float2* __restrict__ wssh,
    const int* __restrict__ es, int i0, int i1,
    const ushort_t* __restrict__ Kt, const ushort_t* __restrict__ Vt,
    float pscale, int lane, int koff,
    float& m, float& plsum, float2& acc)
{
    const int epar = lane >> 5;
    const int dpair = (lane & 31) << 1;
    for (int c = i0; c < i1; c += 64) {
        const int e = c + lane;
        const bool valid = e < i1;
        const int sidx = valid ? es[e] : 0;
        const uint4* kr = (const uint4*)(Kt + ((size_t)sidx << 8) + koff);
        float d0 = 0.f, d1 = 0.f;
#pragma unroll
        for (int u = 0; u < 8; u++) {
            const uint4 kv = kr[u];
            const float4 qa = *(const float4*)(qsh + (u << 3));
            const float4 qb = *(const float4*)(qsh + (u << 3) + 4);
            float dd = (u & 1) ? d1 : d0;
            dd = fmaf(bflo(kv.x), qa.x, dd); dd = fmaf(bfhi(kv.x), qa.y, dd);
            dd = fmaf(bflo(kv.y), qa.z, dd); dd = fmaf(bfhi(kv.y), qa.w, dd);
            dd = fmaf(bflo(kv.z), qb.x, dd); dd = fmaf(bfhi(kv.z), qb.y, dd);
            dd = fmaf(bflo(kv.w), qb.z, dd); dd = fmaf(bfhi(kv.w), qb.w, dd);
            if (u & 1) d1 = dd; else d0 = dd;
        }
        const float a = valid ? (d0 + d1) * pscale : -INFINITY;
        float cm = a;
#pragma unroll
        for (int o = 32; o; o >>= 1) cm = fmaxf(cm, __shfl_xor(cm, o));
        const float mn = fmaxf(m, cm);
        const float sc = (m == -INFINITY) ? 0.f : expf(m - mn);
        const float w = valid ? expf(a - mn) : 0.f;
        plsum = plsum * sc + w;
        m = mn;
        wssh[lane] = make_float2(w, __int_as_float(sidx));
        acc.x *= sc; acc.y *= sc;
        float2 aE = make_float2(0.f, 0.f), aO = make_float2(0.f, 0.f);
#pragma unroll
        for (int b = 0; b < 64; b += 16) {
            float2 we[8];
            unsigned vv[8];
#pragma unroll
            for (int j = 0; j < 8; j++) we[j] = wssh[b + (j << 1) + epar];
#pragma unroll
            for (int j = 0; j < 8; j++) {
                const int sj = __float_as_int(we[j].y);
                vv[j] = *(const unsigned*)(Vt + (((size_t)sj) << 8) + koff + dpair);
            }
#pragma unroll
            for (int j = 0; j < 8; j++) {
                const float wj = we[j].x;
                if (j & 1) { aO.x = fmaf(wj, bflo(vv[j]), aO.x);
                             aO.y = fmaf(wj, bfhi(vv[j]), aO.y); }
                else       { aE.x = fmaf(wj, bflo(vv[j]), aE.x);
                             aE.y = fmaf(wj, bfhi(vv[j]), aE.y); }
            }
        }
        acc.x += aE.x + aO.x;
        acc.y += aE.y + aO.y;
    }
}

__global__ __launch_bounds__(256) void edge_attn_single(
    const float* __restrict__ Qp, const int* __restrict__ off, const int* __restrict__ es,
    const ushort_t* __restrict__ Kt, const ushort_t* __restrict__ Vt,
    const float* __restrict__ prel, int r, float* __restrict__ out)
{
    __shared__ float qsh[NHEAD][64];
    __shared__ float2 wssh[NHEAD][64];
    const int dstn = blockIdx.x, tid = threadIdx.x, lane = tid & 63, h = tid >> 6;
    const int koff = h << 6;
    qsh[h][lane] = Qp[(size_t)dstn * HIDF + koff + lane];
    const float ps = prel[(r << 2) + h] * ATT_SCALE;
    float m = -INFINITY, plsum = 0.f;
    float2 acc = make_float2(0.f, 0.f);
    edge_seg_v2(qsh[h], wssh[h], es, off[dstn], off[dstn + 1], Kt, Vt, ps, lane, koff,
                m, plsum, acc);
    acc.x += __shfl_xor(acc.x, 32);
    acc.y += __shfl_xor(acc.y, 32);
    float l = plsum;
#pragma unroll
    for (int o = 32; o; o >>= 1) l += __shfl_xor(l, o);
    const float inv = (l > 0.f) ? 1.f / l : 0.f;
    if (lane < 32)
        *(float2*)(out + (size_t)dstn * HIDF + koff + ((lane & 31) << 1)) =
            make_float2(acc.x * inv, acc.y * inv);
}

__global__ __launch_bounds__(512) void edge_attn_dual(
    const float* __restrict__ QpA, const float* __restrict__ QpB,
    const int* __restrict__ offA, const int* __restrict__ esA,
    const int* __restrict__ offB, const int* __restrict__ esB,
    const ushort_t* __restrict__ KA, const ushort_t* __restrict__ VA,
    const ushort_t* __restrict__ KB, const ushort_t* __restrict__ VB,
    const float* __restrict__ prel, int ra, int rb,
    float* __restrict__ outA, float* __restrict__ outB)
{
    __shared__ float qsh[8][64];
    __shared__ float2 wssh[8][64];
    __shared__ float mS[8], lS[8];
    const int dstn = blockIdx.x, tid = threadIdx.x, lane = tid & 63, wv = tid >> 6;
    const int rel = wv >> 2, h = wv & 3, koff = h << 6;
    const float* Qp = rel ? QpB : QpA;
    qsh[wv][lane] = Qp[(size_t)dstn * HIDF + koff + lane];
    const float ps = prel[((rel ? rb : ra) << 2) + h] * ATT_SCALE;
    float m = -INFINITY, plsum = 0.f;
    float2 acc = make_float2(0.f, 0.f);
    if (rel == 0)
        edge_seg_v2(qsh[wv], wssh[wv], esA, offA[dstn], offA[dstn + 1], KA, VA, ps,
                    lane, koff, m, plsum, acc);
    else
        edge_seg_v2(qsh[wv], wssh[wv], esB, offB[dstn], offB[dstn + 1], KB, VB, ps,
                    lane, koff, m, plsum, acc);
    acc.x += __shfl_xor(acc.x, 32);
    acc.y += __shfl_xor(acc.y, 32);
    float l = plsum;
#pragma unroll
    for (int o = 32; o; o >>= 1) l += __shfl_xor(l, o);
    if (lane == 0) { mS[wv] = m; lS[wv] = l; }
    __syncthreads();
    const float mo = mS[wv ^ 4], lo = lS[wv ^ 4];
    const float mn = fmaxf(m, mo);
    const float s  = (m  == -INFINITY) ? 0.f : expf(m - mn);
    const float so = (mo == -INFINITY) ? 0.f : expf(mo - mn);
    const float L = l * s + lo * so;
    const float factor = (L > 0.f) ? s / L : 0.f;
    float* out = rel ? outB : outA;
    if (lane < 32)
        *(float2*)(out + (size_t)dstn * HIDF + koff + ((lane & 31) << 1)) =
            make_float2(acc.x * factor, acc.y * factor);
}

// ---------------------------------------------------------------------------
// [N][256] fp32 -> [4][N][64] bf16 (optionally scaled)
__global__ void cast_split_kernel(const float* __restrict__ in, ushort_t* __restrict__ out,
                                  int Nrows, float scale)
{
    int i = blockIdx.x * 256 + threadIdx.x;
    if (i < Nrows * HIDF) {
        const int n = i >> 8, c = i & 255, hh = c >> 6, d = c & 63;
        out[((size_t)hh * Nrows + n) * 64 + d] = f2bf(in[i] * scale);
    }
}

// [N][256] fp32 -> [4][64][N] bf16 (per-head transpose)
__global__ __launch_bounds__(256) void transposeV_kernel(
    const float* __restrict__ in, ushort_t* __restrict__ out, int Nrows)
{
    __shared__ float Ls[64][65];
    const int h = blockIdx.y, n0 = blockIdx.x << 6, tid = threadIdx.x;
    const int c = tid & 63, rq = tid >> 6;
    for (int rr = rq; rr < 64; rr += 4)
        Ls[rr][c] = in[(size_t)(n0 + rr) * HIDF + (h << 6) + c];
    __syncthreads();
    for (int dd = rq; dd < 64; dd += 4)
        out[((size_t)(h * 64 + dd)) * Nrows + n0 + c] = f2bf(Ls[c][dd]);
}

// ---------------------------------------------------------------------------
// Flash cross-attention with intra-block split-K.
// Grid (Nq/16, NHEAD); 4 waves, wave w owns keys [w*Nk/4,(w+1)*Nk/4);
// 16 q-rows per block; flash (m,l,o) combine across waves in LDS.
__global__ __launch_bounds__(256) void flash_ca(
    const ushort_t* __restrict__ qh, const ushort_t* __restrict__ kh,
    const ushort_t* __restrict__ vT, float* __restrict__ O, int Nq, int Nk)
{
    __shared__ ushort_t Pl[4][16][72];
    __shared__ float mS[4][16], lS[4][16];
    __shared__ float oS[4][16][64];
    const int head = blockIdx.y;
    const int q0 = blockIdx.x << 4;
    const int tid = threadIdx.x, wave = tid >> 6, lane = tid & 63;
    const int l15 = lane & 15, lg = lane >> 4;

    const ushort_t* qbase = qh + ((size_t)head * Nq + q0 + l15) * 64 + (lg << 3);
    const bf16x8 qa0 = *(const bf16x8*)qbase;
    const bf16x8 qa1 = *(const bf16x8*)(qbase + 32);
    const ushort_t* kbase = kh + (size_t)head * Nk * 64;
    const ushort_t* vbase = vT + (size_t)head * 64 * Nk;
    const int kchunk = Nk >> 2;
    const int kbeg = wave * kchunk, kend = kbeg + kchunk;

    f32x4 o[4] = {{0,0,0,0},{0,0,0,0},{0,0,0,0},{0,0,0,0}};
    float m[4]    = {-INFINITY, -INFINITY, -INFINITY, -INFINITY};
    float lsum[4] = {0.f, 0.f, 0.f, 0.f};

    for (int k0 = kbeg; k0 < kend; k0 += 64) {
        f32x4 s[4] = {{0,0,0,0},{0,0,0,0},{0,0,0,0},{0,0,0,0}};
        const ushort_t* krow = kbase + ((size_t)(k0 + l15)) * 64 + (lg << 3);
#pragma unroll
        for (int ct = 0; ct < 4; ct++) {
            const bf16x8 b = *(const bf16x8*)(krow + (ct << 10));
            s[ct] = __builtin_amdgcn_mfma_f32_16x16x32_bf16(qa0, b, s[ct], 0, 0, 0);
        }
#pragma unroll
        for (int ct = 0; ct < 4; ct++) {
            const bf16x8 b = *(const bf16x8*)(krow + (ct << 10) + 32);
            s[ct] = __builtin_amdgcn_mfma_f32_16x16x32_bf16(qa1, b, s[ct], 0, 0, 0);
        }
        float tm[4], sc[4], ts[4];
#pragma unroll
        for (int r = 0; r < 4; r++)
            tm[r] = fmaxf(fmaxf(s[0][r], s[1][r]), fmaxf(s[2][r], s[3][r]));
#pragma unroll
        for (int off = 1; off <= 8; off <<= 1)
#pragma unroll
            for (int r = 0; r < 4; r++)
                tm[r] = fmaxf(tm[r], __shfl_xor(tm[r], off));
#pragma unroll
        for (int r = 0; r < 4; r++) {
            const float mn = fmaxf(m[r], tm[r]);
            sc[r] = expf(m[r] - mn);
            m[r] = mn;
            ts[r] = 0.f;
        }
#pragma unroll
        for (int ct = 0; ct < 4; ct++)
#pragma unroll
            for (int r = 0; r < 4; r++) {
                const float p = expf(s[ct][r] - m[r]);
                ts[r] += p;
                Pl[wave][(lg << 2) + r][(ct << 4) + l15] = f2bf(p);
            }
#pragma unroll
        for (int off = 1; off <= 8; off <<= 1)
#pragma unroll
            for (int r = 0; r < 4; r++)
                ts[r] += __shfl_xor(ts[r], off);
#pragma unroll
        for (int r = 0; r < 4; r++)
            lsum[r] = lsum[r] * sc[r] + ts[r];
#pragma unroll
        for (int vt = 0; vt < 4; vt++)
#pragma unroll
            for (int r = 0; r < 4; r++)
                o[vt][r] *= sc[r];
        const bf16x8 pa0 = *(const bf16x8*)&Pl[wave][l15][lg << 3];
        const bf16x8 pa1 = *(const bf16x8*)&Pl[wave][l15][32 + (lg << 3)];
        const ushort_t* vrow = vbase + (size_t)l15 * Nk + k0 + (lg << 3);
#pragma unroll
        for (int vt = 0; vt < 4; vt++) {
            const bf16x8 b = *(const bf16x8*)(vrow + (size_t)(vt << 4) * Nk);
            o[vt] = __builtin_amdgcn_mfma_f32_16x16x32_bf16(pa0, b, o[vt], 0, 0, 0);
        }
#pragma unroll
        for (int vt = 0; vt < 4; vt++) {
            const bf16x8 b = *(const bf16x8*)(vrow + (size_t)(vt << 4) * Nk + 32);
            o[vt] = __builtin_amdgcn_mfma_f32_16x16x32_bf16(pa1, b, o[vt], 0, 0, 0);
        }
    }
    // ---- cross-wave flash combine ----
    if (l15 == 0) {
#pragma unroll
        for (int r = 0; r < 4; r++) {
            mS[wave][(lg << 2) + r] = m[r];
            lS[wave][(lg << 2) + r] = lsum[r];
        }
    }
    __syncthreads();
    float fac[4];
#pragma unroll
    for (int r = 0; r < 4; r++) {
        const int row = (lg << 2) + r;
        const float ms = fmaxf(fmaxf(mS[0][row], mS[1][row]),
                               fmaxf(mS[2][row], mS[3][row]));
        fac[r] = expf(m[r] - ms);
    }
#pragma unroll
    for (int vt = 0; vt < 4; vt++)
#pragma unroll
        for (int r = 0; r < 4; r++)
            oS[wave][(lg << 2) + r][(vt << 4) + l15] = o[vt][r] * fac[r];
    __syncthreads();
    for (int i = tid; i < 1024; i += 256) {
        const int row = i >> 6, d = i & 63;
        const float m0 = mS[0][row], m1 = mS[1][row], m2 = mS[2][row], m3 = mS[3][row];
        const float ms = fmaxf(fmaxf(m0, m1), fmaxf(m2, m3));
        const float L = lS[0][row] * expf(m0 - ms) + lS[1][row] * expf(m1 - ms)
                      + lS[2][row] * expf(m2 - ms) + lS[3][row] * expf(m3 - ms);
        const float val = oS[0][row][d] + oS[1][row][d] + oS[2][row][d] + oS[3][row][d];
        O[(size_t)(q0 + row) * HIDF + (head << 6) + d] = val / L;
    }
}

// ---------------------------------------------------------------------------
// Fused residual + LayerNorm + exact GELU (in-place update of h).
__global__ __launch_bounds__(256) void ln_gelu_kernel(
    float* __restrict__ h, const float* __restrict__ hg,
    const float* __restrict__ g, const float* __restrict__ b)
{
    __shared__ float t4[4];
    const int row = blockIdx.x, tid = threadIdx.x, lane = tid & 63, w = tid >> 6;
    const size_t idx = (size_t)row * HIDF + tid;
    const float x = h[idx] + hg[idx];
    float v = x;
#pragma unroll
    for (int o = 32; o; o >>= 1) v += __shfl_xor(v, o);
    if (lane == 0) t4[w] = v;
    __syncthreads();
    const float mean = (t4[0] + t4[1] + t4[2] + t4[3]) * (1.f / 256.f);
    __syncthreads();
    const float d = x - mean;
    v = d * d;
#pragma unroll
    for (int o = 32; o; o >>= 1) v += __shfl_xor(v, o);
    if (lane == 0) t4[w] = v;
    __syncthreads();
    const float var = (t4[0] + t4[1] + t4[2] + t4[3]) * (1.f / 256.f);
    const float y = d * rsqrtf(var + 1e-5f) * g[tid] + b[tid];
    h[idx] = gelu_exact(y);
}

// ---------------------------------------------------------------------------
extern "C" void kernel_launch(void* const* d_in, const int* in_sizes, int n_in,
                              void* d_out, int out_size, void* d_ws, size_t ws_size,
                              hipStream_t stream)
{
    (void)in_sizes; (void)n_in; (void)out_size; (void)ws_size;
    const float* x_p   = (const float*)d_in[0];
    const float* x_g   = (const float*)d_in[1];
    const float* x_m   = (const float*)d_in[2];
    const int*  src_pg = (const int*)d_in[3];
    const int*  dst_pg = (const int*)d_in[4];
    const int*  src_gp = (const int*)d_in[5];
    const int*  dst_gp = (const int*)d_in[6];
    const int*  src_pm = (const int*)d_in[7];
    const int*  dst_pm = (const int*)d_in[8];
    const int*  src_mp = (const int*)d_in[9];
    const int*  dst_mp = (const int*)d_in[10];
    const float* Win_p = (const float*)d_in[11];
    const float* bin_p = (const float*)d_in[12];
    const float* Win_g = (const float*)d_in[13];
    const float* bin_g = (const float*)d_in[14];
    const float* Win_m = (const float*)d_in[15];
    const float* bin_m = (const float*)d_in[16];
    const float* kw    = (const float*)d_in[17];
    const float* qw    = (const float*)d_in[18];
    const float* vw    = (const float*)d_in[19];
    const float* aw    = (const float*)d_in[20];
    const float* kb    = (const float*)d_in[21];
    const float* qb    = (const float*)d_in[22];
    const float* vb    = (const float*)d_in[23];
    const float* ab    = (const float*)d_in[24];
    const float* skip  = (const float*)d_in[25];
    const float* a_rel = (const float*)d_in[26];
    const float* m_rel = (const float*)d_in[27];
    const float* p_rel = (const float*)d_in[28];
    const float* ca_qw = (const float*)d_in[29];
    const float* ca_kw = (const float*)d_in[30];
    const float* ca_vw = (const float*)d_in[31];
    const float* ca_ow = (const float*)d_in[32];
    const float* ca_qb = (const float*)d_in[33];
    const float* ca_kb = (const float*)d_in[34];
    const float* ca_vb = (const float*)d_in[35];
    const float* ca_ob = (const float*)d_in[36];
    const float* ln_g  = (const float*)d_in[37];
    const float* ln_b  = (const float*)d_in[38];
    const float* outw  = (const float*)d_in[39];
    const float* outb  = (const float*)d_in[40];
    float* dout = (float*)d_out;

    // ---- workspace carve-up ----
    float* Wp = (float*)d_ws;
    size_t cursz = 0;
    auto alloc = [&](size_t n) -> float* {
        float* p = Wp + cursz; cursz += (n + 63) & ~(size_t)63; return p;
    };
    const size_t NT = N0 + N1 + N2;               // 9216
    float* h0  = alloc((size_t)N0 * HIDF);
    float* h1  = alloc((size_t)N1 * HIDF);
    float* h2  = alloc((size_t)N2 * HIDF);
    float* hg0 = alloc((size_t)N0 * HIDF);
    float* hg1 = alloc((size_t)N1 * HIDF);
    float* hg2 = alloc((size_t)N2 * HIDF);
    float* Q0  = alloc((size_t)N0 * HIDF);
    float* Q1  = alloc((size_t)N1 * HIDF);
    float* Q2  = alloc((size_t)N2 * HIDF);
    ushort_t* K16 = (ushort_t*)alloc(NT * HIDF / 2);
    ushort_t* V16 = (ushort_t*)alloc(NT * HIDF / 2);
    ushort_t* K16_0 = K16, *K16_1 = K16 + (size_t)N0 * HIDF, *K16_2 = K16 + (size_t)(N0 + N1) * HIDF;
    ushort_t* V16_0 = V16, *V16_1 = V16 + (size_t)N0 * HIDF, *V16_2 = V16 + (size_t)(N0 + N1) * HIDF;
    float* QpPool  = alloc((size_t)(N1 + N0 + N2 + N0) * HIDF);   // 13312 rows
    float* Qp0 = QpPool;
    float* Qp1 = Qp0 + (size_t)N1 * HIDF;
    float* Qp2 = Qp1 + (size_t)N0 * HIDF;
    float* Qp3 = Qp2 + (size_t)N2 * HIDF;
    float* PartPool = alloc((size_t)(N0 + N0 + N1 + N2) * HIDF);  // 11264 rows
    float* pA0 = PartPool;
    float* pB0 = pA0 + (size_t)N0 * HIDF;
    float* p1  = pB0 + (size_t)N0 * HIDF;
    float* p2  = p1 + (size_t)N1 * HIDF;
    float* agg0 = alloc(NT * HIDF);
    float* agg1 = agg0 + (size_t)N0 * HIDF;
    float* agg2 = agg1 + (size_t)N1 * HIDF;
    ushort_t* hb   = (ushort_t*)alloc(NT * HIDF / 2);             // bf16 h
    ushort_t* WT16 = (ushort_t*)alloc(2621440 / 2);               // bf16 W^T (all mats)
    // bf16 x inputs alias QpPool (dead before layer loop)
    ushort_t* xb = (ushort_t*)QpPool;
    const size_t xoff0 = 0, xoff1 = (size_t)N0 * 512, xoff2 = xoff1 + (size_t)N1 * 768;
    // bf16 gelu(agg) + bf16 cao alias PartPool (dead during those phases)
    ushort_t* aggb16 = (ushort_t*)PartPool;
    ushort_t* caob16 = (ushort_t*)(PartPool + (size_t)1300000);
    // CA fp32 buffers alias Qp pool (dead during cross-attention)
    float* caq = QpPool;
    float* cak = caq + (size_t)N1 * HIDF;
    float* cav = cak + (size_t)N0 * HIDF;
    float* cao = cav + (size_t)N0 * HIDF;
    // CA bf16 tables alias agg (dead during cross-attention)
    ushort_t* qh16 = (ushort_t*)agg0;
    ushort_t* kh16 = qh16 + (size_t)NHEAD * N1 * HDIM;
    ushort_t* vT16 = kh16 + (size_t)NHEAD * N0 * HDIM;
    int* es_gp = (int*)alloc(E_GP);
    int* es_mp = (int*)alloc(E_MP);
    int* es_pg = (int*)alloc(E_PG);
    int* es_pm = (int*)alloc(E_PM);
    int* off_gp = (int*)alloc(N0 + 1); int* cur_gp = (int*)alloc(N0);
    int* off_mp = (int*)alloc(N0 + 1); int* cur_mp = (int*)alloc(N0);
    int* off_pg = (int*)alloc(N1 + 1); int* cur_pg = (int*)alloc(N1);
    int* off_pm = (int*)alloc(N2 + 1); int* cur_pm = (int*)alloc(N2);

    // WT16 sub-offsets (ushort units)
    ushort_t* qwT    = WT16;
    ushort_t* kwT    = WT16 + 6 * 65536;
    ushort_t* vwT    = WT16 + 12 * 65536;
    ushort_t* awT    = WT16 + 18 * 65536;
    ushort_t* ca_qwT = WT16 + 24 * 65536;
    ushort_t* ca_kwT = WT16 + 26 * 65536;
    ushort_t* ca_vwT = WT16 + 28 * 65536;
    ushort_t* ca_owT = WT16 + 30 * 65536;
    ushort_t* outwT  = WT16 + 32 * 65536;
    ushort_t* WinTp  = outwT + 3 * 32768;
    ushort_t* WinTg  = WinTp + 256 * 512;
    ushort_t* WinTm  = WinTg + 256 * 768;

    // ---- weight transpose+cast (all 38 matrices, once) ----
    {
        TWDescArr<38> T;
        for (int i = 0; i < 6; i++) {
            T.d[i]      = { qw + (size_t)i * 65536, qwT + (size_t)i * 65536, 256, 256 };
            T.d[6 + i]  = { kw + (size_t)i * 65536, kwT + (size_t)i * 65536, 256, 256 };
            T.d[12 + i] = { vw + (size_t)i * 65536, vwT + (size_t)i * 65536, 256, 256 };
            T.d[18 + i] = { aw + (size_t)i * 65536, awT + (size_t)i * 65536, 256, 256 };
        }
        for (int c = 0; c < 2; c++) {
            T.d[24 + c] = { ca_qw + (size_t)c * 65536, ca_qwT + (size_t)c * 65536, 256, 256 };
            T.d[26 + c] = { ca_kw + (size_t)c * 65536, ca_kwT + (size_t)c * 65536, 256, 256 };
            T.d[28 + c] = { ca_vw + (size_t)c * 65536, ca_vwT + (size_t)c * 65536, 256, 256 };
            T.d[30 + c] = { ca_ow + (size_t)c * 65536, ca_owT + (size_t)c * 65536, 256, 256 };
        }
        for (int t = 0; t < 3; t++)
            T.d[32 + t] = { outw + (size_t)t * 32768, outwT + (size_t)t * 32768, 256, 128 };
        T.d[35] = { Win_p, WinTp, 512, 256 };
        T.d[36] = { Win_g, WinTg, 768, 256 };
        T.d[37] = { Win_m, WinTm, 384, 256 };
        transW_kernel<38><<<dim3(12, 4, 38), 256, 0, stream>>>(T);
    }

    // ---- counting-sort edges by destination (4 independent CSRs) ----
    hipMemsetAsync(cur_gp, 0, N0 * sizeof(int), stream);
    count_kernel<<<(E_GP + 255) / 256, 256, 0, stream>>>(dst_gp, E_GP, cur_gp);
    scan_kernel<<<1, 256, 0, stream>>>(cur_gp, N0, off_gp);
    scatter_kernel<<<(E_GP + 255) / 256, 256, 0, stream>>>(src_gp, dst_gp, E_GP, cur_gp, es_gp);

    hipMemsetAsync(cur_mp, 0, N0 * sizeof(int), stream);
    count_kernel<<<(E_MP + 255) / 256, 256, 0, stream>>>(dst_mp, E_MP, cur_mp);
    scan_kernel<<<1, 256, 0, stream>>>(cur_mp, N0, off_mp);
    scatter_kernel<<<(E_MP + 255) / 256, 256, 0, stream>>>(src_mp, dst_mp, E_MP, cur_mp, es_mp);

    hipMemsetAsync(cur_pg, 0, N1 * sizeof(int), stream);
    count_kernel<<<(E_PG + 255) / 256, 256, 0, stream>>>(dst_pg, E_PG, cur_pg);
    scan_kernel<<<1, 256, 0, stream>>>(cur_pg, N1, off_pg);
    scatter_kernel<<<(E_PG + 255) / 256, 256, 0, stream>>>(src_pg, dst_pg, E_PG, cur_pg, es_pg);

    hipMemsetAsync(cur_pm, 0, N2 * sizeof(int), stream);
    count_kernel<<<(E_PM + 255) / 256, 256, 0, stream>>>(dst_pm, E_PM, cur_pm);
    scan_kernel<<<1, 256, 0, stream>>>(cur_pm, N2, off_pm);
    scatter_kernel<<<(E_PM + 255) / 256, 256, 0, stream>>>(src_pm, dst_pm, E_PM, cur_pm, es_pm);

    // ---- input projections (bf16 MFMA) ----
    cast_bf16_kernel<false><<<(N0 * 512 / 4 + 255) / 256, 256, 0, stream>>>(x_p, xb + xoff0, N0 * 512 / 4);
    cast_bf16_kernel<false><<<(N1 * 768 / 4 + 255) / 256, 256, 0, stream>>>(x_g, xb + xoff1, N1 * 768 / 4);
    cast_bf16_kernel<false><<<(N2 * 384 / 4 + 255) / 256, 256, 0, stream>>>(x_m, xb + xoff2, N2 * 384 / 4);
    {
        MGemmDescArr<3> D;
        D.d[0] = { xb + xoff0, WinTp, h0, bin_p, nullptr, nullptr, N0, 512 };
        D.d[1] = { xb + xoff1, WinTg, h1, bin_g, nullptr, nullptr, N1, 768 };
        D.d[2] = { xb + xoff2, WinTm, h2, bin_m, nullptr, nullptr, N2, 384 };
        gemm_mfma<3, M_STORE><<<dim3(4, 64, 3), 256, 0, stream>>>(D, HIDF);
    }

    float* hptr[3]  = { h0, h1, h2 };
    float* hgptr[3] = { hg0, hg1, hg2 };
    float* Qptr[3]  = { Q0, Q1, Q2 };
    ushort_t* Kp[3] = { K16_0, K16_1, K16_2 };
    ushort_t* Vp[3] = { V16_0, V16_1, V16_2 };
    const int Ns[3] = { N0, N1, N2 };
    const size_t hoff[3] = { 0, (size_t)N0 * HIDF, (size_t)(N0 + N1) * HIDF };

    for (int l = 0; l < 2; l++) {
        // bf16 cast of h (serves QKV and CA projections; h is stable till LN)
        cast_bf16_kernel<false><<<((int)(NT * HIDF / 4) + 255) / 256, 256, 0, stream>>>(h0, hb, (int)(NT * HIDF / 4));
        // Q projections (fp32 out, feeds Q' transform)
        {
            MGemmDescArr<3> D;
            for (int t = 0; t < 3; t++)
                D.d[t] = { hb + hoff[t], qwT + (size_t)(l * 3 + t) * 65536, Qptr[t],
                           qb + (size_t)(l * 3 + t) * HIDF, nullptr, nullptr, Ns[t], HIDF };
            gemm_mfma<3, M_STORE><<<dim3(4, 64, 3), 256, 0, stream>>>(D, HIDF);
        }
        // K/V projections -> bf16 gather tables
        {
            MGemmDescArr<6> D;
            for (int t = 0; t < 3; t++) {
                D.d[t]     = { hb + hoff[t], kwT + (size_t)(l * 3 + t) * 65536, Kp[t],
                               kb + (size_t)(l * 3 + t) * HIDF, nullptr, nullptr, Ns[t], HIDF };
                D.d[3 + t] = { hb + hoff[t], vwT + (size_t)(l * 3 + t) * 65536, Vp[t],
                               vb + (size_t)(l * 3 + t) * HIDF, nullptr, nullptr, Ns[t], HIDF };
            }
            gemm_mfma<6, M_B16><<<dim3(4, 64, 6), 256, 0, stream>>>(D, HIDF);
        }
        // Q' = a_rel[h] @ Q per dst node (trw=1), 4 relations in one launch
        {
            const float* ar = a_rel + (size_t)l * 4 * 16384;
            RelDesc2Arr<4> R;
            R.d[0] = { Q1, ar + 0 * 16384, nullptr, nullptr, Qp0, N1, 1 };
            R.d[1] = { Q0, ar + 1 * 16384, nullptr, nullptr, Qp1, N0, 1 };
            R.d[2] = { Q2, ar + 2 * 16384, nullptr, nullptr, Qp2, N2, 1 };
            R.d[3] = { Q0, ar + 3 * 16384, nullptr, nullptr, Qp3, N0, 1 };
            rel2_kernel<4><<<dim3(N1 / 16, NHEAD, 4), 256, 0, stream>>>(R);
        }
        // segment-softmax edge attention (raw-V partial sums per relation)
        const float* prl = p_rel + (size_t)l * 16;
        edge_attn_dual<<<N0, 512, 0, stream>>>(Qp1, Qp3, off_gp, es_gp, off_mp, es_mp,
                                               K16_1, V16_1, K16_2, V16_2, prl, 1, 3, pA0, pB0);
        edge_attn_single<<<N1, 256, 0, stream>>>(Qp0, off_pg, es_pg, K16_0, V16_0, prl, 0, p1);
        edge_attn_single<<<N2, 256, 0, stream>>>(Qp2, off_pm, es_pm, K16_0, V16_0, prl, 2, p2);
        // agg = sum_r partial_r @ m_rel[r]
        {
            const float* mr = m_rel + (size_t)l * 4 * 16384;
            RelDesc2Arr<3> R;
            R.d[0] = { pA0, mr + 1 * 16384, pB0, mr + 3 * 16384, agg0, N0, 0 };
            R.d[1] = { p1,  mr + 0 * 16384, nullptr, nullptr,    agg1, N1, 0 };
            R.d[2] = { p2,  mr + 2 * 16384, nullptr, nullptr,    agg2, N2, 0 };
            rel2_kernel<3><<<dim3(N1 / 16, NHEAD, 3), 256, 0, stream>>>(R);
        }
        // gelu(agg) fused into bf16 cast (PartPool now dead)
        cast_bf16_kernel<true><<<((int)(NT * HIDF / 4) + 255) / 256, 256, 0, stream>>>(agg0, aggb16, (int)(NT * HIDF / 4));
        // hg = sigmoid(skip)*(gelu(agg) @ aw + ab) + (1-sigmoid(skip))*h
        {
            MGemmDescArr<3> D;
            for (int t = 0; t < 3; t++)
                D.d[t] = { aggb16 + hoff[t], awT + (size_t)(l * 3 + t) * 65536, hgptr[t],
                           ab + (size_t)(l * 3 + t) * HIDF, skip + l * 3 + t, hptr[t], Ns[t], HIDF };
            gemm_mfma<3, M_SKIP><<<dim3(4, 64, 3), 256, 0, stream>>>(D, HIDF);
        }

        // cross attention: types 1,2 attend to participants (h0)
        for (int t = 1; t <= 2; t++) {
            const int c = t - 1, Nq = Ns[t];
            {
                MGemmDescArr<3> D;
                D.d[0] = { hb + hoff[t], ca_qwT + (size_t)c * 65536, caq, ca_qb + c * HIDF, nullptr, nullptr, Nq, HIDF };
                D.d[1] = { hb,           ca_kwT + (size_t)c * 65536, cak, ca_kb + c * HIDF, nullptr, nullptr, N0, HIDF };
                D.d[2] = { hb,           ca_vwT + (size_t)c * 65536, cav, ca_vb + c * HIDF, nullptr, nullptr, N0, HIDF };
                gemm_mfma<3, M_STORE><<<dim3(4, Nq / 64, 3), 256, 0, stream>>>(D, HIDF);
            }
            cast_split_kernel<<<(Nq * HIDF + 255) / 256, 256, 0, stream>>>(caq, qh16, Nq, ATT_SCALE);
            cast_split_kernel<<<(N0 * HIDF + 255) / 256, 256, 0, stream>>>(cak, kh16, N0, 1.0f);
            transposeV_kernel<<<dim3(N0 / 64, NHEAD), 256, 0, stream>>>(cav, vT16, N0);
            flash_ca<<<dim3(Nq / 16, NHEAD), 256, 0, stream>>>(qh16, kh16, vT16, cao, Nq, N0);
            cast_bf16_kernel<false><<<(Nq * HIDF / 4 + 255) / 256, 256, 0, stream>>>(cao, caob16, Nq * HIDF / 4);
            {
                MGemmDescArr<1> D;
                D.d[0] = { caob16, ca_owT + (size_t)c * 65536, hgptr[t], ca_ob + c * HIDF, nullptr, nullptr, Nq, HIDF };
                gemm_mfma<1, M_ADD><<<dim3(4, Nq / 64, 1), 256, 0, stream>>>(D, HIDF);
            }
        }

        // h = gelu(LN(h + hg))
        for (int t = 0; t < 3; t++)
            ln_gelu_kernel<<<Ns[t], 256, 0, stream>>>(hptr[t], hgptr[t], ln_g + t * HIDF, ln_b + t * HIDF);
    }

    // ---- output projections (bf16 MFMA, N=128) ----
    cast_bf16_kernel<false><<<((int)(NT * HIDF / 4) + 255) / 256, 256, 0, stream>>>(h0, hb, (int)(NT * HIDF / 4));
    {
        MGemmDescArr<3> D;
        D.d[0] = { hb,           outwT + 0,     dout,                            outb,       nullptr, nullptr, N0, HIDF };
        D.d[1] = { hb + hoff[1], outwT + 32768, dout + (size_t)N0 * OUTF,        outb + 128, nullptr, nullptr, N1, HIDF };
        D.d[2] = { hb + hoff[2], outwT + 65536, dout + (size_t)(N0 + N1) * OUTF, outb + 256, nullptr, nullptr, N2, HIDF };
        gemm_mfma<3, M_STORE><<<dim3(2, 64, 3), 256, 0, stream>>>(D, OUTF);
    }
}